// Round 6
// baseline (15358.504 us; speedup 1.0000x reference)
//
#include <hip/hip_runtime.h>
#include <hip/hip_bf16.h>
#include <hip/hip_cooperative_groups.h>

namespace cg = cooperative_groups;

typedef __attribute__((ext_vector_type(8))) short short8;
typedef __attribute__((ext_vector_type(4))) float f32x4;
typedef __hip_bfloat16 bf16_t;

#define BATCH 4096
#define ISZ 64
#define HSZ 256
#define TSZ 64

__device__ __forceinline__ float sigm(float x) { return 1.f / (1.f + __expf(-x)); }
__device__ __forceinline__ float tanh_fast(float x) { return 1.f - 2.f / (1.f + __expf(2.f * x)); }

// split a double into 3 bf16 planes (repr error ~2^-26 relative)
__device__ __forceinline__ void split3(double x, bf16_t& p0, bf16_t& p1, bf16_t& p2) {
  p0 = __float2bfloat16((float)x);
  double r1 = x - (double)__bfloat162float(p0);
  p1 = __float2bfloat16((float)r1);
  double r2 = r1 - (double)__bfloat162float(p1);
  p2 = __float2bfloat16((float)r2);
}

// ---------------- spectral norm prep, fp64 (1 block) ----------------
__global__ __launch_bounds__(256) void prep_sn(
    const float* __restrict__ w_lin, const float* __restrict__ u_sn,
    double* __restrict__ w_sn_f64)
{
  __shared__ double v[HSZ];
  __shared__ double red[256];
  __shared__ double Wv[ISZ];
  int t = threadIdx.x;
  double s = 0.0;
  for (int i = 0; i < ISZ; ++i) s += (double)w_lin[i * HSZ + t] * (double)u_sn[i];
  red[t] = s * s;
  __syncthreads();
  for (int off = 128; off > 0; off >>= 1) { if (t < off) red[t] += red[t + off]; __syncthreads(); }
  double nv = sqrt(red[0]);
  v[t] = s / (nv + 1e-12);
  __syncthreads();
  {
    int i = t >> 2, p = t & 3;
    double ps = 0.0;
    for (int k = p * 64; k < p * 64 + 64; ++k) ps += (double)w_lin[i * HSZ + k] * v[k];
    red[t] = ps;
    __syncthreads();
    if ((t & 3) == 0) Wv[i] = red[t] + red[t + 1] + red[t + 2] + red[t + 3];
    __syncthreads();
  }
  red[t] = (t < ISZ) ? Wv[t] * Wv[t] : 0.0;
  __syncthreads();
  for (int off = 128; off > 0; off >>= 1) { if (t < off) red[t] += red[t + off]; __syncthreads(); }
  double nw = sqrt(red[0]);
  double sigma = red[0] / (nw + 1e-12);  // u.(Wv), u = Wv/(|Wv|+eps)
  double inv_sigma = 1.0 / sigma;
  for (int idx = t; idx < ISZ * HSZ; idx += 256)
    w_sn_f64[idx] = (double)w_lin[idx] * inv_sigma;
}

// ---------------- 2-plane split casts ----------------
__global__ __launch_bounds__(256) void split2_f32(
    const float* __restrict__ x, bf16_t* __restrict__ p0, bf16_t* __restrict__ p1, int n)
{
  int i = blockIdx.x * 256 + threadIdx.x;
  if (i < n) {
    float v = x[i];
    bf16_t a = __float2bfloat16(v);
    p0[i] = a;
    p1[i] = __float2bfloat16(v - __bfloat162float(a));
  }
}

__global__ __launch_bounds__(256) void split2_f64(
    const double* __restrict__ x, bf16_t* __restrict__ p0, bf16_t* __restrict__ p1, int n)
{
  int i = blockIdx.x * 256 + threadIdx.x;
  if (i < n) {
    double v = x[i];
    bf16_t a = __float2bfloat16((float)v);
    p0[i] = a;
    p1[i] = __float2bfloat16((float)(v - (double)__bfloat162float(a)));
  }
}

// =================================================================================
// Persistent cooperative kernel: all 64 steps.
// Grid 512 = 32 row-groups x 16 jb; block 256 = 4 waves; 2 blocks/CU (LDS-bound).
// Per step: phase A gates+cell (weights in LDS), grid.sync, phase B y-projection
// (1024 active waves: 256 row16-groups x 4 col-tiles), grid.sync.
// Math identical to the verified R5 kernels.
// =================================================================================
#define WHP (HSZ + 8)  // padded LDS row (bank-conflict-free: stride 132 dwords = 4 mod 32)
#define WIP (ISZ + 8)

__global__ __launch_bounds__(256) void gru_persist(
    const bf16_t* Wi0, const bf16_t* Wi1, const bf16_t* Wh0, const bf16_t* Wh1,
    const bf16_t* Ws0, const bf16_t* Ws1,
    const float* b_ih, const float* b_hh, const float* b_lin,
    bf16_t* X0, bf16_t* X1,
    bf16_t* HA0, bf16_t* HA1, bf16_t* HA2,
    bf16_t* HB0, bf16_t* HB1, bf16_t* HB2,
    float* out)
{
  cg::grid_group grid = cg::this_grid();
  __shared__ __align__(16) short lWh[96 * WHP];
  __shared__ __align__(16) short lWi[96 * WIP];

  const int jb = blockIdx.x >> 5;
  const int rb = blockIdx.x & 31;
  const int tid = threadIdx.x;
  const int wid = tid >> 6;
  const int l = tid & 63;
  const int lr = l & 15;
  const int lq = l >> 4;
  const int mw = rb * 128 + wid * 32;
  const int j = jb * 16 + lr;

  // ---- load weight slices to LDS once (rows r = g*32 + p*16 + jr)
  {
    const short* s0 = (const short*)Wh0;
    const short* s1 = (const short*)Wh1;
    for (int e = tid; e < 96 * 256; e += 256) {
      int r = e >> 8, k = e & 255;
      int g = r >> 5, p = (r >> 4) & 1, jr = r & 15;
      const short* src = p ? s1 : s0;
      lWh[r * WHP + k] = src[(size_t)(g * HSZ + jb * 16 + jr) * HSZ + k];
    }
    const short* t0 = (const short*)Wi0;
    const short* t1 = (const short*)Wi1;
    for (int e = tid; e < 96 * 64; e += 256) {
      int r = e >> 6, k = e & 63;
      int g = r >> 5, p = (r >> 4) & 1, jr = r & 15;
      const short* src = p ? t1 : t0;
      lWi[r * WIP + k] = src[(size_t)(g * HSZ + jb * 16 + jr) * ISZ + k];
    }
  }
  __syncthreads();

  const float brz = b_ih[j] + b_hh[j];
  const float bzz = b_ih[HSZ + j] + b_hh[HSZ + j];
  const float bin = b_ih[2 * HSZ + j];
  const float bhn = b_hh[2 * HSZ + j];

  // phase-B wave task
  const int gw = blockIdx.x * 4 + wid;
  const bool bact = gw < 1024;
  const int brow = (gw >> 2) * 16;
  const int bnt = gw & 3;
  const float bl = b_lin[bnt * 16 + lr];

  for (int t = 0; t < TSZ; ++t) {
    bf16_t* Ho0 = (t & 1) ? HB0 : HA0;
    bf16_t* Ho1 = (t & 1) ? HB1 : HA1;
    bf16_t* Ho2 = (t & 1) ? HB2 : HA2;
    const bf16_t* Hi0 = (t & 1) ? HA0 : HB0;
    const bf16_t* Hi1 = (t & 1) ? HA1 : HB1;
    const bf16_t* Hi2 = (t & 1) ? HA2 : HB2;

    // ================= phase A: gates + cell =================
    f32x4 accM[2][4], accC[2][4];
#pragma unroll
    for (int mt = 0; mt < 2; ++mt)
#pragma unroll
      for (int g = 0; g < 4; ++g) {
        accM[mt][g] = (f32x4){0.f, 0.f, 0.f, 0.f};
        accC[mt][g] = (f32x4){0.f, 0.f, 0.f, 0.f};
      }

    // gi: x @ w_ih.T (K=64)
#pragma unroll
    for (int kk = 0; kk < ISZ; kk += 32) {
      short8 a0[2], a1[2];
#pragma unroll
      for (int mt = 0; mt < 2; ++mt) {
        size_t ao = (size_t)(mw + mt * 16 + lr) * ISZ + kk + lq * 8;
        a0[mt] = *reinterpret_cast<const short8*>(X0 + ao);
        a1[mt] = *reinterpret_cast<const short8*>(X1 + ao);
      }
#pragma unroll
      for (int g = 0; g < 3; ++g) {
        short8 b0 = *reinterpret_cast<const short8*>(&lWi[(g * 32 + lr) * WIP + kk + lq * 8]);
        short8 b1 = *reinterpret_cast<const short8*>(&lWi[(g * 32 + 16 + lr) * WIP + kk + lq * 8]);
#pragma unroll
        for (int mt = 0; mt < 2; ++mt) {
          accC[mt][g] = __builtin_amdgcn_mfma_f32_16x16x32_bf16(a0[mt], b1, accC[mt][g], 0, 0, 0);
          accC[mt][g] = __builtin_amdgcn_mfma_f32_16x16x32_bf16(a1[mt], b0, accC[mt][g], 0, 0, 0);
          accM[mt][g] = __builtin_amdgcn_mfma_f32_16x16x32_bf16(a0[mt], b0, accM[mt][g], 0, 0, 0);
        }
      }
    }

    // gh: h @ w_hh.T (K=256); gate2 -> col 3
    if (t > 0) {
#pragma unroll 2
      for (int kk = 0; kk < HSZ; kk += 32) {
        short8 a0[2], a1[2];
#pragma unroll
        for (int mt = 0; mt < 2; ++mt) {
          size_t ao = (size_t)(mw + mt * 16 + lr) * HSZ + kk + lq * 8;
          a0[mt] = *reinterpret_cast<const short8*>(Hi0 + ao);
          a1[mt] = *reinterpret_cast<const short8*>(Hi1 + ao);
        }
#pragma unroll
        for (int g = 0; g < 3; ++g) {
          const int tgt = (g == 2) ? 3 : g;
          short8 b0 = *reinterpret_cast<const short8*>(&lWh[(g * 32 + lr) * WHP + kk + lq * 8]);
          short8 b1 = *reinterpret_cast<const short8*>(&lWh[(g * 32 + 16 + lr) * WHP + kk + lq * 8]);
#pragma unroll
          for (int mt = 0; mt < 2; ++mt) {
            accC[mt][tgt] = __builtin_amdgcn_mfma_f32_16x16x32_bf16(a0[mt], b1, accC[mt][tgt], 0, 0, 0);
            accC[mt][tgt] = __builtin_amdgcn_mfma_f32_16x16x32_bf16(a1[mt], b0, accC[mt][tgt], 0, 0, 0);
            accM[mt][tgt] = __builtin_amdgcn_mfma_f32_16x16x32_bf16(a0[mt], b0, accM[mt][tgt], 0, 0, 0);
          }
        }
      }
    }

#pragma unroll
    for (int mt = 0; mt < 2; ++mt) {
#pragma unroll
      for (int q = 0; q < 4; ++q) {
        int b = mw + mt * 16 + lq * 4 + q;  // C/D: row=(lane>>4)*4+reg, col=lane&15
        float rpre = accM[mt][0][q] + accC[mt][0][q] + brz;
        float zpre = accM[mt][1][q] + accC[mt][1][q] + bzz;
        float inn = accM[mt][2][q] + accC[mt][2][q] + bin;
        float hnn = accM[mt][3][q] + accC[mt][3][q] + bhn;
        float r = sigm(rpre);
        float z = sigm(zpre);
        float n = tanh_fast(inn + r * hnn);
        size_t idx = (size_t)b * HSZ + j;
        double hold = 0.0;
        if (t > 0)
          hold = (double)__bfloat162float(Hi0[idx]) + (double)__bfloat162float(Hi1[idx]) +
                 (double)__bfloat162float(Hi2[idx]);
        double hv = (double)((1.f - z) * n) + (double)z * hold;
        bf16_t p0, p1, p2;
        split3(hv, p0, p1, p2);
        Ho0[idx] = p0; Ho1[idx] = p1; Ho2[idx] = p2;
      }
    }

    __threadfence();
    grid.sync();

    // ================= phase B: y = h @ w_sn.T + b_lin =================
    if (bact) {
      f32x4 aM = (f32x4){0.f, 0.f, 0.f, 0.f};
      f32x4 aC = (f32x4){0.f, 0.f, 0.f, 0.f};
#pragma unroll 2
      for (int kk = 0; kk < HSZ; kk += 32) {
        size_t ao = (size_t)(brow + lr) * HSZ + kk + lq * 8;
        short8 a0 = *reinterpret_cast<const short8*>(Ho0 + ao);
        short8 a1 = *reinterpret_cast<const short8*>(Ho1 + ao);
        size_t bo = (size_t)(bnt * 16 + lr) * HSZ + kk + lq * 8;
        short8 b0 = *reinterpret_cast<const short8*>(Ws0 + bo);
        short8 b1 = *reinterpret_cast<const short8*>(Ws1 + bo);
        aC = __builtin_amdgcn_mfma_f32_16x16x32_bf16(a0, b1, aC, 0, 0, 0);
        aC = __builtin_amdgcn_mfma_f32_16x16x32_bf16(a1, b0, aC, 0, 0, 0);
        aM = __builtin_amdgcn_mfma_f32_16x16x32_bf16(a0, b0, aM, 0, 0, 0);
      }
      float* yout = out + (size_t)t * BATCH * 64;
#pragma unroll
      for (int q = 0; q < 4; ++q) {
        size_t row = brow + lq * 4 + q;
        int o = bnt * 16 + lr;
        float yf = aM[q] + aC[q] + bl;
        size_t oi = row * 64 + o;
        yout[oi] = yf;
        bf16_t p0 = __float2bfloat16(yf);
        X0[oi] = p0;
        X1[oi] = __float2bfloat16(yf - __bfloat162float(p0));
      }
    }

    __threadfence();
    grid.sync();
  }
}

// ---------------- fallback per-step kernels (R5, proven) ----------------
template <bool FIRST>
__global__ __launch_bounds__(256) void gru_gates(
    const bf16_t* __restrict__ X0, const bf16_t* __restrict__ X1,
    const bf16_t* __restrict__ H0, const bf16_t* __restrict__ H1, const bf16_t* __restrict__ H2,
    const bf16_t* __restrict__ Wi0, const bf16_t* __restrict__ Wi1,
    const bf16_t* __restrict__ Wh0, const bf16_t* __restrict__ Wh1,
    const float* __restrict__ b_ih, const float* __restrict__ b_hh,
    bf16_t* __restrict__ O0, bf16_t* __restrict__ O1, bf16_t* __restrict__ O2)
{
  const int jb = blockIdx.y;
  const int mw = blockIdx.x * 128 + (threadIdx.x >> 6) * 32;
  const int l = threadIdx.x & 63;
  const int lr = l & 15;
  const int lq = l >> 4;
  const int j = jb * 16 + lr;

  f32x4 accM[2][4], accC[2][4];
#pragma unroll
  for (int mt = 0; mt < 2; ++mt)
#pragma unroll
    for (int g = 0; g < 4; ++g) {
      accM[mt][g] = (f32x4){0.f, 0.f, 0.f, 0.f};
      accC[mt][g] = (f32x4){0.f, 0.f, 0.f, 0.f};
    }

#pragma unroll
  for (int kk = 0; kk < ISZ; kk += 32) {
    short8 a0[2], a1[2];
#pragma unroll
    for (int mt = 0; mt < 2; ++mt) {
      size_t ao = (size_t)(mw + mt * 16 + lr) * ISZ + kk + lq * 8;
      a0[mt] = *reinterpret_cast<const short8*>(X0 + ao);
      a1[mt] = *reinterpret_cast<const short8*>(X1 + ao);
    }
#pragma unroll
    for (int g = 0; g < 3; ++g) {
      size_t bo = (size_t)(g * HSZ + jb * 16 + lr) * ISZ + kk + lq * 8;
      short8 b0 = *reinterpret_cast<const short8*>(Wi0 + bo);
      short8 b1 = *reinterpret_cast<const short8*>(Wi1 + bo);
#pragma unroll
      for (int mt = 0; mt < 2; ++mt) {
        accC[mt][g] = __builtin_amdgcn_mfma_f32_16x16x32_bf16(a0[mt], b1, accC[mt][g], 0, 0, 0);
        accC[mt][g] = __builtin_amdgcn_mfma_f32_16x16x32_bf16(a1[mt], b0, accC[mt][g], 0, 0, 0);
        accM[mt][g] = __builtin_amdgcn_mfma_f32_16x16x32_bf16(a0[mt], b0, accM[mt][g], 0, 0, 0);
      }
    }
  }

  if (!FIRST) {
    for (int kk = 0; kk < HSZ; kk += 32) {
      short8 a0[2], a1[2];
#pragma unroll
      for (int mt = 0; mt < 2; ++mt) {
        size_t ao = (size_t)(mw + mt * 16 + lr) * HSZ + kk + lq * 8;
        a0[mt] = *reinterpret_cast<const short8*>(H0 + ao);
        a1[mt] = *reinterpret_cast<const short8*>(H1 + ao);
      }
#pragma unroll
      for (int g = 0; g < 3; ++g) {
        const int tgt = (g == 2) ? 3 : g;
        size_t bo = (size_t)(g * HSZ + jb * 16 + lr) * HSZ + kk + lq * 8;
        short8 b0 = *reinterpret_cast<const short8*>(Wh0 + bo);
        short8 b1 = *reinterpret_cast<const short8*>(Wh1 + bo);
#pragma unroll
        for (int mt = 0; mt < 2; ++mt) {
          accC[mt][tgt] = __builtin_amdgcn_mfma_f32_16x16x32_bf16(a0[mt], b1, accC[mt][tgt], 0, 0, 0);
          accC[mt][tgt] = __builtin_amdgcn_mfma_f32_16x16x32_bf16(a1[mt], b0, accC[mt][tgt], 0, 0, 0);
          accM[mt][tgt] = __builtin_amdgcn_mfma_f32_16x16x32_bf16(a0[mt], b0, accM[mt][tgt], 0, 0, 0);
        }
      }
    }
  }

  const float brz = b_ih[0 * HSZ + j] + b_hh[0 * HSZ + j];
  const float bzz = b_ih[1 * HSZ + j] + b_hh[1 * HSZ + j];
  const float bin = b_ih[2 * HSZ + j];
  const float bhn = b_hh[2 * HSZ + j];

#pragma unroll
  for (int mt = 0; mt < 2; ++mt) {
#pragma unroll
    for (int q = 0; q < 4; ++q) {
      int b = mw + mt * 16 + lq * 4 + q;
      float rpre = accM[mt][0][q] + accC[mt][0][q] + brz;
      float zpre = accM[mt][1][q] + accC[mt][1][q] + bzz;
      float inn = accM[mt][2][q] + accC[mt][2][q] + bin;
      float hnn = accM[mt][3][q] + accC[mt][3][q] + bhn;
      float r = sigm(rpre);
      float z = sigm(zpre);
      float n = tanh_fast(inn + r * hnn);
      size_t idx = (size_t)b * HSZ + j;
      double hold = 0.0;
      if (!FIRST)
        hold = (double)__bfloat162float(H0[idx]) + (double)__bfloat162float(H1[idx]) +
               (double)__bfloat162float(H2[idx]);
      double hv = (double)((1.f - z) * n) + (double)z * hold;
      bf16_t p0, p1, p2;
      split3(hv, p0, p1, p2);
      O0[idx] = p0; O1[idx] = p1; O2[idx] = p2;
    }
  }
}

__global__ __launch_bounds__(64) void y_step(
    const bf16_t* __restrict__ H0, const bf16_t* __restrict__ H1,
    const bf16_t* __restrict__ Ws0, const bf16_t* __restrict__ Ws1,
    const float* __restrict__ b_lin,
    float* __restrict__ yout,
    bf16_t* __restrict__ X0, bf16_t* __restrict__ X1)
{
  const int mw = blockIdx.x * 16;
  const int l = threadIdx.x;
  const int lr = l & 15;
  const int lq = l >> 4;

  f32x4 accM[4], accC[4];
#pragma unroll
  for (int nt = 0; nt < 4; ++nt) {
    accM[nt] = (f32x4){0.f, 0.f, 0.f, 0.f};
    accC[nt] = (f32x4){0.f, 0.f, 0.f, 0.f};
  }

  for (int kk = 0; kk < HSZ; kk += 32) {
    size_t ao = (size_t)(mw + lr) * HSZ + kk + lq * 8;
    short8 a0 = *reinterpret_cast<const short8*>(H0 + ao);
    short8 a1 = *reinterpret_cast<const short8*>(H1 + ao);
#pragma unroll
    for (int nt = 0; nt < 4; ++nt) {
      size_t bo = (size_t)(nt * 16 + lr) * HSZ + kk + lq * 8;
      short8 b0 = *reinterpret_cast<const short8*>(Ws0 + bo);
      short8 b1 = *reinterpret_cast<const short8*>(Ws1 + bo);
      accC[nt] = __builtin_amdgcn_mfma_f32_16x16x32_bf16(a0, b1, accC[nt], 0, 0, 0);
      accC[nt] = __builtin_amdgcn_mfma_f32_16x16x32_bf16(a1, b0, accC[nt], 0, 0, 0);
      accM[nt] = __builtin_amdgcn_mfma_f32_16x16x32_bf16(a0, b0, accM[nt], 0, 0, 0);
    }
  }

#pragma unroll
  for (int q = 0; q < 4; ++q) {
    size_t row = mw + lq * 4 + q;
#pragma unroll
    for (int nt = 0; nt < 4; ++nt) {
      int o = nt * 16 + lr;
      float yf = accM[nt][q] + accC[nt][q] + b_lin[o];
      size_t oi = row * 64 + o;
      yout[oi] = yf;
      bf16_t p0 = __float2bfloat16(yf);
      X0[oi] = p0;
      X1[oi] = __float2bfloat16(yf - __bfloat162float(p0));
    }
  }
}

// ---------------- BatchNorm: two-stage stats + normalize ----------------
__global__ __launch_bounds__(256) void bn_part(const float* __restrict__ Y,
                                               double* __restrict__ psum,
                                               double* __restrict__ psum2)
{
  int t = blockIdx.x;
  int chunk = blockIdx.y;
  int o = threadIdx.x & 63, rg = threadIdx.x >> 6;
  const float* Yt = Y + (size_t)t * BATCH * 64;
  int b0 = chunk * 256;
  double s = 0.0, s2 = 0.0;
  for (int b = b0 + rg; b < b0 + 256; b += 4) {
    double v = (double)Yt[(size_t)b * 64 + o];
    s += v;
    s2 += v * v;
  }
  __shared__ double ls[4][64], ls2[4][64];
  ls[rg][o] = s;
  ls2[rg][o] = s2;
  __syncthreads();
  if (rg == 0) {
    s = ls[0][o] + ls[1][o] + ls[2][o] + ls[3][o];
    s2 = ls2[0][o] + ls2[1][o] + ls2[2][o] + ls2[3][o];
    size_t pi = ((size_t)t * 16 + chunk) * 64 + o;
    psum[pi] = s;
    psum2[pi] = s2;
  }
}

__global__ __launch_bounds__(64) void bn_final(const double* __restrict__ psum,
                                               const double* __restrict__ psum2,
                                               float* __restrict__ mean,
                                               float* __restrict__ istd)
{
  int t = blockIdx.x;
  int o = threadIdx.x;
  double s = 0.0, s2 = 0.0;
  for (int c = 0; c < 16; ++c) {
    size_t pi = ((size_t)t * 16 + c) * 64 + o;
    s += psum[pi];
    s2 += psum2[pi];
  }
  double m = s * (1.0 / BATCH);
  double var = s2 * (1.0 / BATCH) - m * m;
  mean[t * 64 + o] = (float)m;
  istd[t * 64 + o] = (float)(1.0 / sqrt(var + 1e-5));
}

__global__ __launch_bounds__(256) void bn_norm(float* __restrict__ Y,
                                               const float* __restrict__ mean,
                                               const float* __restrict__ istd, int n4)
{
  for (int i = blockIdx.x * 256 + threadIdx.x; i < n4; i += gridDim.x * 256) {
    f32x4 v = reinterpret_cast<f32x4*>(Y)[i];
    int base = i * 4;
    int o = base & 63;
    int t = base >> 18;  // / (BATCH*64)
    const float* mr = mean + t * 64;
    const float* ir = istd + t * 64;
#pragma unroll
    for (int e = 0; e < 4; ++e) v[e] = (v[e] - mr[o + e]) * ir[o + e];
    reinterpret_cast<f32x4*>(Y)[i] = v;
  }
}

extern "C" void kernel_launch(void* const* d_in, const int* in_sizes, int n_in,
                              void* d_out, int out_size, void* d_ws, size_t ws_size,
                              hipStream_t stream)
{
  const float* inputs = (const float*)d_in[0];
  const float* w_ih = (const float*)d_in[1];
  const float* w_hh = (const float*)d_in[2];
  const float* b_ih = (const float*)d_in[3];
  const float* b_hh = (const float*)d_in[4];
  const float* w_lin = (const float*)d_in[5];
  const float* b_lin = (const float*)d_in[6];
  const float* u_sn = (const float*)d_in[7];
  float* out = (float*)d_out;

  const size_t BH = (size_t)BATCH * HSZ;
  const size_t BI = (size_t)BATCH * ISZ;

  char* ws = (char*)d_ws;
  size_t off = 0;
  auto alloc = [&](size_t bytes) -> void* {
    void* p = ws + off;
    off += (bytes + 255) & ~(size_t)255;
    return p;
  };
  double* w_sn_f64 = (double*)alloc((size_t)ISZ * HSZ * 8);
  bf16_t* Wi0 = (bf16_t*)alloc((size_t)3 * HSZ * ISZ * 2);
  bf16_t* Wi1 = (bf16_t*)alloc((size_t)3 * HSZ * ISZ * 2);
  bf16_t* Wh0 = (bf16_t*)alloc((size_t)3 * HSZ * HSZ * 2);
  bf16_t* Wh1 = (bf16_t*)alloc((size_t)3 * HSZ * HSZ * 2);
  bf16_t* Ws0 = (bf16_t*)alloc((size_t)ISZ * HSZ * 2);
  bf16_t* Ws1 = (bf16_t*)alloc((size_t)ISZ * HSZ * 2);
  bf16_t* X0 = (bf16_t*)alloc(BI * 2);
  bf16_t* X1 = (bf16_t*)alloc(BI * 2);
  bf16_t* HA0 = (bf16_t*)alloc(BH * 2);
  bf16_t* HA1 = (bf16_t*)alloc(BH * 2);
  bf16_t* HA2 = (bf16_t*)alloc(BH * 2);
  bf16_t* HB0 = (bf16_t*)alloc(BH * 2);
  bf16_t* HB1 = (bf16_t*)alloc(BH * 2);
  bf16_t* HB2 = (bf16_t*)alloc(BH * 2);
  double* psum = (double*)alloc((size_t)TSZ * 16 * 64 * 8);
  double* psum2 = (double*)alloc((size_t)TSZ * 16 * 64 * 8);
  float* meanb = (float*)alloc(TSZ * 64 * 4);
  float* istdb = (float*)alloc(TSZ * 64 * 4);
  if (off > ws_size) return;

  prep_sn<<<1, 256, 0, stream>>>(w_lin, u_sn, w_sn_f64);
  split2_f32<<<(3 * HSZ * ISZ + 255) / 256, 256, 0, stream>>>(w_ih, Wi0, Wi1, 3 * HSZ * ISZ);
  split2_f32<<<(3 * HSZ * HSZ + 255) / 256, 256, 0, stream>>>(w_hh, Wh0, Wh1, 3 * HSZ * HSZ);
  split2_f64<<<(ISZ * HSZ + 255) / 256, 256, 0, stream>>>(w_sn_f64, Ws0, Ws1, ISZ * HSZ);
  split2_f32<<<((int)BI + 255) / 256, 256, 0, stream>>>(inputs, X0, X1, (int)BI);

  // ---- persistent cooperative recurrence (fallback: per-step loop) ----
  {
    void* args[] = {
        (void*)&Wi0, (void*)&Wi1, (void*)&Wh0, (void*)&Wh1,
        (void*)&Ws0, (void*)&Ws1,
        (void*)&b_ih, (void*)&b_hh, (void*)&b_lin,
        (void*)&X0, (void*)&X1,
        (void*)&HA0, (void*)&HA1, (void*)&HA2,
        (void*)&HB0, (void*)&HB1, (void*)&HB2,
        (void*)&out};
    hipError_t err = hipLaunchCooperativeKernel((void*)gru_persist, dim3(512), dim3(256),
                                                args, 0, stream);
    if (err != hipSuccess) {
      bf16_t *Hin0 = HB0, *Hin1 = HB1, *Hin2 = HB2;
      bf16_t *Hout0 = HA0, *Hout1 = HA1, *Hout2 = HA2;
      const dim3 g1(BATCH / 128, 16);
      for (int t = 0; t < TSZ; ++t) {
        if (t == 0) {
          gru_gates<true><<<g1, 256, 0, stream>>>(
              X0, X1, nullptr, nullptr, nullptr,
              Wi0, Wi1, Wh0, Wh1, b_ih, b_hh, Hout0, Hout1, Hout2);
        } else {
          gru_gates<false><<<g1, 256, 0, stream>>>(
              X0, X1, Hin0, Hin1, Hin2,
              Wi0, Wi1, Wh0, Wh1, b_ih, b_hh, Hout0, Hout1, Hout2);
        }
        y_step<<<BATCH / 16, 64, 0, stream>>>(
            Hout0, Hout1, Ws0, Ws1, b_lin,
            out + (size_t)t * BATCH * 64, X0, X1);
        bf16_t* tm;
        tm = Hin0; Hin0 = Hout0; Hout0 = tm;
        tm = Hin1; Hin1 = Hout1; Hout1 = tm;
        tm = Hin2; Hin2 = Hout2; Hout2 = tm;
      }
    }
  }

  bn_part<<<dim3(TSZ, 16), 256, 0, stream>>>(out, psum, psum2);
  bn_final<<<TSZ, 64, 0, stream>>>(psum, psum2, meanb, istdb);
  bn_norm<<<2048, 256, 0, stream>>>(out, meanb, istdb, TSZ * BATCH * 64 / 4);
}

// Round 8
// 3137.024 us; speedup vs baseline: 4.8959x; 4.8959x over previous
//
#include <hip/hip_runtime.h>
#include <hip/hip_bf16.h>

// R6 post-mortem: grid.sync() costs ~125us on MI355X -- never persistent-coop here.
// R7 post-mortem: folding w_ih@w_sn into the recurrence fails (0.139 absmax, 3rd repro).
//   Only bit-equivalent-to-R5 transformations from here on.

typedef __attribute__((ext_vector_type(8))) short short8;
typedef __attribute__((ext_vector_type(4))) float f32x4;
typedef __hip_bfloat16 bf16_t;

#define BATCH 4096
#define ISZ 64
#define HSZ 256
#define TSZ 64

__device__ __forceinline__ float sigm(float x) { return 1.f / (1.f + __expf(-x)); }
__device__ __forceinline__ float tanh_fast(float x) { return 1.f - 2.f / (1.f + __expf(2.f * x)); }

__device__ __forceinline__ void split3(double x, bf16_t& p0, bf16_t& p1, bf16_t& p2) {
  p0 = __float2bfloat16((float)x);
  double r1 = x - (double)__bfloat162float(p0);
  p1 = __float2bfloat16((float)r1);
  double r2 = r1 - (double)__bfloat162float(p1);
  p2 = __float2bfloat16((float)r2);
}

// ---------------- spectral norm prep, fp64 (1 block) ----------------
__global__ __launch_bounds__(256) void prep_sn(
    const float* __restrict__ w_lin, const float* __restrict__ u_sn,
    double* __restrict__ w_sn_f64)
{
  __shared__ double v[HSZ];
  __shared__ double red[256];
  __shared__ double Wv[ISZ];
  int t = threadIdx.x;
  double s = 0.0;
  for (int i = 0; i < ISZ; ++i) s += (double)w_lin[i * HSZ + t] * (double)u_sn[i];
  red[t] = s * s;
  __syncthreads();
  for (int off = 128; off > 0; off >>= 1) { if (t < off) red[t] += red[t + off]; __syncthreads(); }
  double nv = sqrt(red[0]);
  v[t] = s / (nv + 1e-12);
  __syncthreads();
  {
    int i = t >> 2, p = t & 3;
    double ps = 0.0;
    for (int k = p * 64; k < p * 64 + 64; ++k) ps += (double)w_lin[i * HSZ + k] * v[k];
    red[t] = ps;
    __syncthreads();
    if ((t & 3) == 0) Wv[i] = red[t] + red[t + 1] + red[t + 2] + red[t + 3];
    __syncthreads();
  }
  red[t] = (t < ISZ) ? Wv[t] * Wv[t] : 0.0;
  __syncthreads();
  for (int off = 128; off > 0; off >>= 1) { if (t < off) red[t] += red[t + off]; __syncthreads(); }
  double nw = sqrt(red[0]);
  double sigma = red[0] / (nw + 1e-12);  // u.(Wv), u = Wv/(|Wv|+eps)
  double inv_sigma = 1.0 / sigma;
  for (int idx = t; idx < ISZ * HSZ; idx += 256)
    w_sn_f64[idx] = (double)w_lin[idx] * inv_sigma;
}

// ---------------- 2-plane split casts ----------------
__global__ __launch_bounds__(256) void split2_f32(
    const float* __restrict__ x, bf16_t* __restrict__ p0, bf16_t* __restrict__ p1, int n)
{
  int i = blockIdx.x * 256 + threadIdx.x;
  if (i < n) {
    float v = x[i];
    bf16_t a = __float2bfloat16(v);
    p0[i] = a;
    p1[i] = __float2bfloat16(v - __bfloat162float(a));
  }
}

__global__ __launch_bounds__(256) void split2_f64(
    const double* __restrict__ x, bf16_t* __restrict__ p0, bf16_t* __restrict__ p1, int n)
{
  int i = blockIdx.x * 256 + threadIdx.x;
  if (i < n) {
    double v = x[i];
    bf16_t a = __float2bfloat16((float)v);
    p0[i] = a;
    p1[i] = __float2bfloat16((float)(v - (double)__bfloat162float(a)));
  }
}

// ---------------- t=0 kernel (R5 gru_gates<true>, unchanged) ----------------
__global__ __launch_bounds__(256) void gru_first(
    const bf16_t* __restrict__ X0, const bf16_t* __restrict__ X1,
    const bf16_t* __restrict__ Wi0, const bf16_t* __restrict__ Wi1,
    const float* __restrict__ b_ih, const float* __restrict__ b_hh,
    bf16_t* __restrict__ O0, bf16_t* __restrict__ O1, bf16_t* __restrict__ O2)
{
  const int jb = blockIdx.y;
  const int mw = blockIdx.x * 128 + (threadIdx.x >> 6) * 32;
  const int l = threadIdx.x & 63;
  const int lr = l & 15;
  const int lq = l >> 4;
  const int j = jb * 16 + lr;

  f32x4 accM[2][3], accC[2][3];
#pragma unroll
  for (int mt = 0; mt < 2; ++mt)
#pragma unroll
    for (int g = 0; g < 3; ++g) {
      accM[mt][g] = (f32x4){0.f, 0.f, 0.f, 0.f};
      accC[mt][g] = (f32x4){0.f, 0.f, 0.f, 0.f};
    }

#pragma unroll
  for (int kk = 0; kk < ISZ; kk += 32) {
    short8 a0[2], a1[2];
#pragma unroll
    for (int mt = 0; mt < 2; ++mt) {
      size_t ao = (size_t)(mw + mt * 16 + lr) * ISZ + kk + lq * 8;
      a0[mt] = *reinterpret_cast<const short8*>(X0 + ao);
      a1[mt] = *reinterpret_cast<const short8*>(X1 + ao);
    }
#pragma unroll
    for (int g = 0; g < 3; ++g) {
      size_t bo = (size_t)(g * HSZ + jb * 16 + lr) * ISZ + kk + lq * 8;
      short8 b0 = *reinterpret_cast<const short8*>(Wi0 + bo);
      short8 b1 = *reinterpret_cast<const short8*>(Wi1 + bo);
#pragma unroll
      for (int mt = 0; mt < 2; ++mt) {
        accC[mt][g] = __builtin_amdgcn_mfma_f32_16x16x32_bf16(a0[mt], b1, accC[mt][g], 0, 0, 0);
        accC[mt][g] = __builtin_amdgcn_mfma_f32_16x16x32_bf16(a1[mt], b0, accC[mt][g], 0, 0, 0);
        accM[mt][g] = __builtin_amdgcn_mfma_f32_16x16x32_bf16(a0[mt], b0, accM[mt][g], 0, 0, 0);
      }
    }
  }

  const float brz = b_ih[j] + b_hh[j];
  const float bzz = b_ih[HSZ + j] + b_hh[HSZ + j];
  const float bin = b_ih[2 * HSZ + j];
  const float bhn = b_hh[2 * HSZ + j];

#pragma unroll
  for (int mt = 0; mt < 2; ++mt) {
#pragma unroll
    for (int q = 0; q < 4; ++q) {
      int b = mw + mt * 16 + lq * 4 + q;
      float r = sigm(accM[mt][0][q] + accC[mt][0][q] + brz);
      float z = sigm(accM[mt][1][q] + accC[mt][1][q] + bzz);
      float n = tanh_fast(accM[mt][2][q] + accC[mt][2][q] + bin + r * bhn);
      double hv = (double)((1.f - z) * n);
      size_t idx = (size_t)b * HSZ + j;
      bf16_t p0, p1, p2;
      split3(hv, p0, p1, p2);
      O0[idx] = p0; O1[idx] = p1; O2[idx] = p2;
    }
  }
}

// ---------------- fused step (t>=1): y_{t-1} + gi + gh + cell ----------------
// Phase 1 (merged with gh K-loop): Y = h_t @ w_sn.T (+b_lin) -- identical math to R5
//   y_step; yf written to out[t-1] by jb==0 blocks; split2(yf) -> X tile in LDS.
// Phase 2: gi = X_lds @ w_ih.T (K=64).  Cell identical to R5.
// Grid (32, 16); block 256 = 4 waves; wave = 32 rows (2 mt tiles).
#define XPAD 72  // 64 + 8 shorts: conflict-optimal b128 reads

__global__ __launch_bounds__(256) void gru_step_fused(
    const bf16_t* __restrict__ Hi0, const bf16_t* __restrict__ Hi1, const bf16_t* __restrict__ Hi2,
    const bf16_t* __restrict__ Wh0, const bf16_t* __restrict__ Wh1,
    const bf16_t* __restrict__ Wi0, const bf16_t* __restrict__ Wi1,
    const bf16_t* __restrict__ Ws0, const bf16_t* __restrict__ Ws1,
    const float* __restrict__ b_ih, const float* __restrict__ b_hh,
    const float* __restrict__ b_lin,
    bf16_t* __restrict__ Ho0, bf16_t* __restrict__ Ho1, bf16_t* __restrict__ Ho2,
    float* __restrict__ yout)  // out + (t-1)*BATCH*64
{
  __shared__ short xl[2 * 4 * 32 * XPAD];  // [plane][wave][row][col]

  const int jb = blockIdx.y;
  const int wid = threadIdx.x >> 6;
  const int mw = blockIdx.x * 128 + wid * 32;
  const int l = threadIdx.x & 63;
  const int lr = l & 15;
  const int lq = l >> 4;
  const int j = jb * 16 + lr;

  // ---- merged K=256 loop: gh accs + Y accs share A-fragments
  f32x4 gM[2][3], gC[2][3];  // gh (r,z,n)
  f32x4 yM[2][4], yC[2][4];  // y (4 col-tiles of 16)
#pragma unroll
  for (int mt = 0; mt < 2; ++mt) {
#pragma unroll
    for (int g = 0; g < 3; ++g) {
      gM[mt][g] = (f32x4){0.f, 0.f, 0.f, 0.f};
      gC[mt][g] = (f32x4){0.f, 0.f, 0.f, 0.f};
    }
#pragma unroll
    for (int nt = 0; nt < 4; ++nt) {
      yM[mt][nt] = (f32x4){0.f, 0.f, 0.f, 0.f};
      yC[mt][nt] = (f32x4){0.f, 0.f, 0.f, 0.f};
    }
  }

  for (int kk = 0; kk < HSZ; kk += 32) {
    short8 a0[2], a1[2];
#pragma unroll
    for (int mt = 0; mt < 2; ++mt) {
      size_t ao = (size_t)(mw + mt * 16 + lr) * HSZ + kk + lq * 8;
      a0[mt] = *reinterpret_cast<const short8*>(Hi0 + ao);
      a1[mt] = *reinterpret_cast<const short8*>(Hi1 + ao);
    }
#pragma unroll
    for (int g = 0; g < 3; ++g) {
      size_t bo = (size_t)(g * HSZ + jb * 16 + lr) * HSZ + kk + lq * 8;
      short8 b0 = *reinterpret_cast<const short8*>(Wh0 + bo);
      short8 b1 = *reinterpret_cast<const short8*>(Wh1 + bo);
#pragma unroll
      for (int mt = 0; mt < 2; ++mt) {
        gC[mt][g] = __builtin_amdgcn_mfma_f32_16x16x32_bf16(a0[mt], b1, gC[mt][g], 0, 0, 0);
        gC[mt][g] = __builtin_amdgcn_mfma_f32_16x16x32_bf16(a1[mt], b0, gC[mt][g], 0, 0, 0);
        gM[mt][g] = __builtin_amdgcn_mfma_f32_16x16x32_bf16(a0[mt], b0, gM[mt][g], 0, 0, 0);
      }
    }
#pragma unroll
    for (int nt = 0; nt < 4; ++nt) {
      size_t bo = (size_t)(nt * 16 + lr) * HSZ + kk + lq * 8;
      short8 b0 = *reinterpret_cast<const short8*>(Ws0 + bo);
      short8 b1 = *reinterpret_cast<const short8*>(Ws1 + bo);
#pragma unroll
      for (int mt = 0; mt < 2; ++mt) {
        yC[mt][nt] = __builtin_amdgcn_mfma_f32_16x16x32_bf16(a0[mt], b1, yC[mt][nt], 0, 0, 0);
        yC[mt][nt] = __builtin_amdgcn_mfma_f32_16x16x32_bf16(a1[mt], b0, yC[mt][nt], 0, 0, 0);
        yM[mt][nt] = __builtin_amdgcn_mfma_f32_16x16x32_bf16(a0[mt], b0, yM[mt][nt], 0, 0, 0);
      }
    }
  }

  // ---- finish y: write out (jb==0) + X tile to LDS (split2 of fp32 y)
  float blv[4];
#pragma unroll
  for (int nt = 0; nt < 4; ++nt) blv[nt] = b_lin[nt * 16 + lr];

#pragma unroll
  for (int mt = 0; mt < 2; ++mt)
#pragma unroll
    for (int q = 0; q < 4; ++q) {
      int lrow = mt * 16 + lq * 4 + q;  // row within wave tile (0..31)
#pragma unroll
      for (int nt = 0; nt < 4; ++nt) {
        int col = nt * 16 + lr;
        float yf = yM[mt][nt][q] + yC[mt][nt][q] + blv[nt];
        if (jb == 0) yout[(size_t)(mw + lrow) * 64 + col] = yf;
        bf16_t p0 = __float2bfloat16(yf);
        bf16_t p1 = __float2bfloat16(yf - __bfloat162float(p0));
        int base = wid * (32 * XPAD) + lrow * XPAD + col;
        xl[base] = *reinterpret_cast<short*>(&p0);
        xl[4 * 32 * XPAD + base] = *reinterpret_cast<short*>(&p1);
      }
    }
  __syncthreads();

  // ---- gi = X_lds @ w_ih.T (K=64)
  f32x4 iM[2][3], iC[2][3];
#pragma unroll
  for (int mt = 0; mt < 2; ++mt)
#pragma unroll
    for (int g = 0; g < 3; ++g) {
      iM[mt][g] = (f32x4){0.f, 0.f, 0.f, 0.f};
      iC[mt][g] = (f32x4){0.f, 0.f, 0.f, 0.f};
    }

#pragma unroll
  for (int kk = 0; kk < ISZ; kk += 32) {
    short8 a0[2], a1[2];
#pragma unroll
    for (int mt = 0; mt < 2; ++mt) {
      int base = wid * (32 * XPAD) + (mt * 16 + lr) * XPAD + kk + lq * 8;
      a0[mt] = *reinterpret_cast<const short8*>(&xl[base]);
      a1[mt] = *reinterpret_cast<const short8*>(&xl[4 * 32 * XPAD + base]);
    }
#pragma unroll
    for (int g = 0; g < 3; ++g) {
      size_t bo = (size_t)(g * HSZ + jb * 16 + lr) * ISZ + kk + lq * 8;
      short8 b0 = *reinterpret_cast<const short8*>(Wi0 + bo);
      short8 b1 = *reinterpret_cast<const short8*>(Wi1 + bo);
#pragma unroll
      for (int mt = 0; mt < 2; ++mt) {
        iC[mt][g] = __builtin_amdgcn_mfma_f32_16x16x32_bf16(a0[mt], b1, iC[mt][g], 0, 0, 0);
        iC[mt][g] = __builtin_amdgcn_mfma_f32_16x16x32_bf16(a1[mt], b0, iC[mt][g], 0, 0, 0);
        iM[mt][g] = __builtin_amdgcn_mfma_f32_16x16x32_bf16(a0[mt], b0, iM[mt][g], 0, 0, 0);
      }
    }
  }

  // ---- cell (R5 formulas)
  const float brz = b_ih[j] + b_hh[j];
  const float bzz = b_ih[HSZ + j] + b_hh[HSZ + j];
  const float bin = b_ih[2 * HSZ + j];
  const float bhn = b_hh[2 * HSZ + j];

#pragma unroll
  for (int mt = 0; mt < 2; ++mt) {
#pragma unroll
    for (int q = 0; q < 4; ++q) {
      int b = mw + mt * 16 + lq * 4 + q;
      float rpre = iM[mt][0][q] + iC[mt][0][q] + gM[mt][0][q] + gC[mt][0][q] + brz;
      float zpre = iM[mt][1][q] + iC[mt][1][q] + gM[mt][1][q] + gC[mt][1][q] + bzz;
      float inn  = iM[mt][2][q] + iC[mt][2][q] + bin;
      float hnn  = gM[mt][2][q] + gC[mt][2][q] + bhn;
      float r = sigm(rpre);
      float z = sigm(zpre);
      float n = tanh_fast(inn + r * hnn);
      size_t idx = (size_t)b * HSZ + j;
      double hold = (double)__bfloat162float(Hi0[idx]) + (double)__bfloat162float(Hi1[idx]) +
                    (double)__bfloat162float(Hi2[idx]);
      double hv = (double)((1.f - z) * n) + (double)z * hold;
      bf16_t p0, p1, p2;
      split3(hv, p0, p1, p2);
      Ho0[idx] = p0; Ho1[idx] = p1; Ho2[idx] = p2;
    }
  }
}

// ---------------- final y (out[63]) : 1024 one-wave blocks, 16 rows x 16 cols ----------------
__global__ __launch_bounds__(64) void y_final(
    const bf16_t* __restrict__ H0, const bf16_t* __restrict__ H1,
    const bf16_t* __restrict__ Ws0, const bf16_t* __restrict__ Ws1,
    const float* __restrict__ b_lin,
    float* __restrict__ yout)
{
  const int rg = blockIdx.x >> 2;
  const int nt = blockIdx.x & 3;
  const int mw = rg * 16;
  const int l = threadIdx.x;
  const int lr = l & 15;
  const int lq = l >> 4;

  f32x4 aM = (f32x4){0.f, 0.f, 0.f, 0.f};
  f32x4 aC = (f32x4){0.f, 0.f, 0.f, 0.f};
#pragma unroll 2
  for (int kk = 0; kk < HSZ; kk += 32) {
    size_t ao = (size_t)(mw + lr) * HSZ + kk + lq * 8;
    short8 a0 = *reinterpret_cast<const short8*>(H0 + ao);
    short8 a1 = *reinterpret_cast<const short8*>(H1 + ao);
    size_t bo = (size_t)(nt * 16 + lr) * HSZ + kk + lq * 8;
    short8 b0 = *reinterpret_cast<const short8*>(Ws0 + bo);
    short8 b1 = *reinterpret_cast<const short8*>(Ws1 + bo);
    aC = __builtin_amdgcn_mfma_f32_16x16x32_bf16(a0, b1, aC, 0, 0, 0);
    aC = __builtin_amdgcn_mfma_f32_16x16x32_bf16(a1, b0, aC, 0, 0, 0);
    aM = __builtin_amdgcn_mfma_f32_16x16x32_bf16(a0, b0, aM, 0, 0, 0);
  }
  int o = nt * 16 + lr;
  float bl = b_lin[o];
#pragma unroll
  for (int q = 0; q < 4; ++q)
    yout[(size_t)(mw + lq * 4 + q) * 64 + o] = aM[q] + aC[q] + bl;
}

// ---------------- BatchNorm: two-stage stats + normalize ----------------
__global__ __launch_bounds__(256) void bn_part(const float* __restrict__ Y,
                                               double* __restrict__ psum,
                                               double* __restrict__ psum2)
{
  int t = blockIdx.x;
  int chunk = blockIdx.y;
  int o = threadIdx.x & 63, rg = threadIdx.x >> 6;
  const float* Yt = Y + (size_t)t * BATCH * 64;
  int b0 = chunk * 256;
  double s = 0.0, s2 = 0.0;
  for (int b = b0 + rg; b < b0 + 256; b += 4) {
    double v = (double)Yt[(size_t)b * 64 + o];
    s += v;
    s2 += v * v;
  }
  __shared__ double ls[4][64], ls2[4][64];
  ls[rg][o] = s;
  ls2[rg][o] = s2;
  __syncthreads();
  if (rg == 0) {
    s = ls[0][o] + ls[1][o] + ls[2][o] + ls[3][o];
    s2 = ls2[0][o] + ls2[1][o] + ls2[2][o] + ls2[3][o];
    size_t pi = ((size_t)t * 16 + chunk) * 64 + o;
    psum[pi] = s;
    psum2[pi] = s2;
  }
}

__global__ __launch_bounds__(64) void bn_final(const double* __restrict__ psum,
                                               const double* __restrict__ psum2,
                                               float* __restrict__ mean,
                                               float* __restrict__ istd)
{
  int t = blockIdx.x;
  int o = threadIdx.x;
  double s = 0.0, s2 = 0.0;
  for (int c = 0; c < 16; ++c) {
    size_t pi = ((size_t)t * 16 + c) * 64 + o;
    s += psum[pi];
    s2 += psum2[pi];
  }
  double m = s * (1.0 / BATCH);
  double var = s2 * (1.0 / BATCH) - m * m;
  mean[t * 64 + o] = (float)m;
  istd[t * 64 + o] = (float)(1.0 / sqrt(var + 1e-5));
}

__global__ __launch_bounds__(256) void bn_norm(float* __restrict__ Y,
                                               const float* __restrict__ mean,
                                               const float* __restrict__ istd, int n4)
{
  for (int i = blockIdx.x * 256 + threadIdx.x; i < n4; i += gridDim.x * 256) {
    f32x4 v = reinterpret_cast<f32x4*>(Y)[i];
    int base = i * 4;
    int o = base & 63;
    int t = base >> 18;  // / (BATCH*64)
    const float* mr = mean + t * 64;
    const float* ir = istd + t * 64;
#pragma unroll
    for (int e = 0; e < 4; ++e) v[e] = (v[e] - mr[o + e]) * ir[o + e];
    reinterpret_cast<f32x4*>(Y)[i] = v;
  }
}

extern "C" void kernel_launch(void* const* d_in, const int* in_sizes, int n_in,
                              void* d_out, int out_size, void* d_ws, size_t ws_size,
                              hipStream_t stream)
{
  const float* inputs = (const float*)d_in[0];
  const float* w_ih = (const float*)d_in[1];
  const float* w_hh = (const float*)d_in[2];
  const float* b_ih = (const float*)d_in[3];
  const float* b_hh = (const float*)d_in[4];
  const float* w_lin = (const float*)d_in[5];
  const float* b_lin = (const float*)d_in[6];
  const float* u_sn = (const float*)d_in[7];
  float* out = (float*)d_out;

  const size_t BH = (size_t)BATCH * HSZ;
  const size_t BI = (size_t)BATCH * ISZ;

  char* ws = (char*)d_ws;
  size_t off = 0;
  auto alloc = [&](size_t bytes) -> void* {
    void* p = ws + off;
    off += (bytes + 255) & ~(size_t)255;
    return p;
  };
  double* w_sn_f64 = (double*)alloc((size_t)ISZ * HSZ * 8);
  bf16_t* Wi0 = (bf16_t*)alloc((size_t)3 * HSZ * ISZ * 2);
  bf16_t* Wi1 = (bf16_t*)alloc((size_t)3 * HSZ * ISZ * 2);
  bf16_t* Wh0 = (bf16_t*)alloc((size_t)3 * HSZ * HSZ * 2);
  bf16_t* Wh1 = (bf16_t*)alloc((size_t)3 * HSZ * HSZ * 2);
  bf16_t* Ws0 = (bf16_t*)alloc((size_t)ISZ * HSZ * 2);
  bf16_t* Ws1 = (bf16_t*)alloc((size_t)ISZ * HSZ * 2);
  bf16_t* X0 = (bf16_t*)alloc(BI * 2);
  bf16_t* X1 = (bf16_t*)alloc(BI * 2);
  bf16_t* HA0 = (bf16_t*)alloc(BH * 2);
  bf16_t* HA1 = (bf16_t*)alloc(BH * 2);
  bf16_t* HA2 = (bf16_t*)alloc(BH * 2);
  bf16_t* HB0 = (bf16_t*)alloc(BH * 2);
  bf16_t* HB1 = (bf16_t*)alloc(BH * 2);
  bf16_t* HB2 = (bf16_t*)alloc(BH * 2);
  double* psum = (double*)alloc((size_t)TSZ * 16 * 64 * 8);
  double* psum2 = (double*)alloc((size_t)TSZ * 16 * 64 * 8);
  float* meanb = (float*)alloc(TSZ * 64 * 4);
  float* istdb = (float*)alloc(TSZ * 64 * 4);
  if (off > ws_size) return;

  prep_sn<<<1, 256, 0, stream>>>(w_lin, u_sn, w_sn_f64);
  split2_f32<<<(3 * HSZ * ISZ + 255) / 256, 256, 0, stream>>>(w_ih, Wi0, Wi1, 3 * HSZ * ISZ);
  split2_f32<<<(3 * HSZ * HSZ + 255) / 256, 256, 0, stream>>>(w_hh, Wh0, Wh1, 3 * HSZ * HSZ);
  split2_f64<<<(ISZ * HSZ + 255) / 256, 256, 0, stream>>>(w_sn_f64, Ws0, Ws1, ISZ * HSZ);
  split2_f32<<<((int)BI + 255) / 256, 256, 0, stream>>>(inputs, X0, X1, (int)BI);

  const dim3 g1(BATCH / 128, 16);

  // t = 0
  gru_first<<<g1, 256, 0, stream>>>(X0, X1, Wi0, Wi1, b_ih, b_hh, HA0, HA1, HA2);

  bf16_t *Hin0 = HA0, *Hin1 = HA1, *Hin2 = HA2;
  bf16_t *Hout0 = HB0, *Hout1 = HB1, *Hout2 = HB2;
  for (int t = 1; t < TSZ; ++t) {
    gru_step_fused<<<g1, 256, 0, stream>>>(
        Hin0, Hin1, Hin2, Wh0, Wh1, Wi0, Wi1, Ws0, Ws1,
        b_ih, b_hh, b_lin, Hout0, Hout1, Hout2,
        out + (size_t)(t - 1) * BATCH * 64);
    bf16_t* tm;
    tm = Hin0; Hin0 = Hout0; Hout0 = tm;
    tm = Hin1; Hin1 = Hout1; Hout1 = tm;
    tm = Hin2; Hin2 = Hout2; Hout2 = tm;
  }
  y_final<<<1024, 64, 0, stream>>>(Hin0, Hin1, Ws0, Ws1, b_lin,
                                   out + (size_t)(TSZ - 1) * BATCH * 64);

  bn_part<<<dim3(TSZ, 16), 256, 0, stream>>>(out, psum, psum2);
  bn_final<<<TSZ, 64, 0, stream>>>(psum, psum2, meanb, istdb);
  bn_norm<<<2048, 256, 0, stream>>>(out, meanb, istdb, TSZ * BATCH * 64 / 4);
}

// Round 9
// 2915.241 us; speedup vs baseline: 5.2683x; 1.0761x over previous
//
#include <hip/hip_runtime.h>
#include <hip/hip_bf16.h>

// R6: grid.sync() ~125us on MI355X -- never persistent-coop for a tight recurrence.
// R7: folding w_ih@w_sn into the recurrence fails numerically (0.139, 3x repro).
//     Only bit-equivalent-to-R5 transformations.
// R8: fused step regressed -- FETCH 7.3MB/dispatch = H planes crossing XCDs (writer's
//     L2 != reader's L2 -> ~900cy latency on GEMM A-operand), 16x redundant y, 10% occ.
// R9: XCD-affine block mapping (row-group pinned to one XCD), 4 blocks/CU, y redundancy
//     16x->4x, X via per-block LDS. Same fp op order -> same absmax.

typedef __attribute__((ext_vector_type(8))) short short8;
typedef __attribute__((ext_vector_type(4))) float f32x4;
typedef __hip_bfloat16 bf16_t;

#define BATCH 4096
#define ISZ 64
#define HSZ 256
#define TSZ 64

__device__ __forceinline__ float sigm(float x) { return 1.f / (1.f + __expf(-x)); }
__device__ __forceinline__ float tanh_fast(float x) { return 1.f - 2.f / (1.f + __expf(2.f * x)); }

__device__ __forceinline__ void split3(double x, bf16_t& p0, bf16_t& p1, bf16_t& p2) {
  p0 = __float2bfloat16((float)x);
  double r1 = x - (double)__bfloat162float(p0);
  p1 = __float2bfloat16((float)r1);
  double r2 = r1 - (double)__bfloat162float(p1);
  p2 = __float2bfloat16((float)r2);
}

// ---------------- spectral norm prep, fp64 (1 block) ----------------
__global__ __launch_bounds__(256) void prep_sn(
    const float* __restrict__ w_lin, const float* __restrict__ u_sn,
    double* __restrict__ w_sn_f64)
{
  __shared__ double v[HSZ];
  __shared__ double red[256];
  __shared__ double Wv[ISZ];
  int t = threadIdx.x;
  double s = 0.0;
  for (int i = 0; i < ISZ; ++i) s += (double)w_lin[i * HSZ + t] * (double)u_sn[i];
  red[t] = s * s;
  __syncthreads();
  for (int off = 128; off > 0; off >>= 1) { if (t < off) red[t] += red[t + off]; __syncthreads(); }
  double nv = sqrt(red[0]);
  v[t] = s / (nv + 1e-12);
  __syncthreads();
  {
    int i = t >> 2, p = t & 3;
    double ps = 0.0;
    for (int k = p * 64; k < p * 64 + 64; ++k) ps += (double)w_lin[i * HSZ + k] * v[k];
    red[t] = ps;
    __syncthreads();
    if ((t & 3) == 0) Wv[i] = red[t] + red[t + 1] + red[t + 2] + red[t + 3];
    __syncthreads();
  }
  red[t] = (t < ISZ) ? Wv[t] * Wv[t] : 0.0;
  __syncthreads();
  for (int off = 128; off > 0; off >>= 1) { if (t < off) red[t] += red[t + off]; __syncthreads(); }
  double nw = sqrt(red[0]);
  double sigma = red[0] / (nw + 1e-12);  // u.(Wv), u = Wv/(|Wv|+eps)
  double inv_sigma = 1.0 / sigma;
  for (int idx = t; idx < ISZ * HSZ; idx += 256)
    w_sn_f64[idx] = (double)w_lin[idx] * inv_sigma;
}

// ---------------- 2-plane split casts ----------------
__global__ __launch_bounds__(256) void split2_f32(
    const float* __restrict__ x, bf16_t* __restrict__ p0, bf16_t* __restrict__ p1, int n)
{
  int i = blockIdx.x * 256 + threadIdx.x;
  if (i < n) {
    float v = x[i];
    bf16_t a = __float2bfloat16(v);
    p0[i] = a;
    p1[i] = __float2bfloat16(v - __bfloat162float(a));
  }
}

__global__ __launch_bounds__(256) void split2_f64(
    const double* __restrict__ x, bf16_t* __restrict__ p0, bf16_t* __restrict__ p1, int n)
{
  int i = blockIdx.x * 256 + threadIdx.x;
  if (i < n) {
    double v = x[i];
    bf16_t a = __float2bfloat16((float)v);
    p0[i] = a;
    p1[i] = __float2bfloat16((float)(v - (double)__bfloat162float(a)));
  }
}

// ---------------- t=0 kernel (R5 gru_gates<true>, unchanged) ----------------
__global__ __launch_bounds__(256) void gru_first(
    const bf16_t* __restrict__ X0, const bf16_t* __restrict__ X1,
    const bf16_t* __restrict__ Wi0, const bf16_t* __restrict__ Wi1,
    const float* __restrict__ b_ih, const float* __restrict__ b_hh,
    bf16_t* __restrict__ O0, bf16_t* __restrict__ O1, bf16_t* __restrict__ O2)
{
  const int jb = blockIdx.y;
  const int mw = blockIdx.x * 128 + (threadIdx.x >> 6) * 32;
  const int l = threadIdx.x & 63;
  const int lr = l & 15;
  const int lq = l >> 4;
  const int j = jb * 16 + lr;

  f32x4 accM[2][3], accC[2][3];
#pragma unroll
  for (int mt = 0; mt < 2; ++mt)
#pragma unroll
    for (int g = 0; g < 3; ++g) {
      accM[mt][g] = (f32x4){0.f, 0.f, 0.f, 0.f};
      accC[mt][g] = (f32x4){0.f, 0.f, 0.f, 0.f};
    }

#pragma unroll
  for (int kk = 0; kk < ISZ; kk += 32) {
    short8 a0[2], a1[2];
#pragma unroll
    for (int mt = 0; mt < 2; ++mt) {
      size_t ao = (size_t)(mw + mt * 16 + lr) * ISZ + kk + lq * 8;
      a0[mt] = *reinterpret_cast<const short8*>(X0 + ao);
      a1[mt] = *reinterpret_cast<const short8*>(X1 + ao);
    }
#pragma unroll
    for (int g = 0; g < 3; ++g) {
      size_t bo = (size_t)(g * HSZ + jb * 16 + lr) * ISZ + kk + lq * 8;
      short8 b0 = *reinterpret_cast<const short8*>(Wi0 + bo);
      short8 b1 = *reinterpret_cast<const short8*>(Wi1 + bo);
#pragma unroll
      for (int mt = 0; mt < 2; ++mt) {
        accC[mt][g] = __builtin_amdgcn_mfma_f32_16x16x32_bf16(a0[mt], b1, accC[mt][g], 0, 0, 0);
        accC[mt][g] = __builtin_amdgcn_mfma_f32_16x16x32_bf16(a1[mt], b0, accC[mt][g], 0, 0, 0);
        accM[mt][g] = __builtin_amdgcn_mfma_f32_16x16x32_bf16(a0[mt], b0, accM[mt][g], 0, 0, 0);
      }
    }
  }

  const float brz = b_ih[j] + b_hh[j];
  const float bzz = b_ih[HSZ + j] + b_hh[HSZ + j];
  const float bin = b_ih[2 * HSZ + j];
  const float bhn = b_hh[2 * HSZ + j];

#pragma unroll
  for (int mt = 0; mt < 2; ++mt) {
#pragma unroll
    for (int q = 0; q < 4; ++q) {
      int b = mw + mt * 16 + lq * 4 + q;
      float r = sigm(accM[mt][0][q] + accC[mt][0][q] + brz);
      float z = sigm(accM[mt][1][q] + accC[mt][1][q] + bzz);
      float n = tanh_fast(accM[mt][2][q] + accC[mt][2][q] + bin + r * bhn);
      double hv = (double)((1.f - z) * n);
      size_t idx = (size_t)b * HSZ + j;
      bf16_t p0, p1, p2;
      split3(hv, p0, p1, p2);
      O0[idx] = p0; O1[idx] = p1; O2[idx] = p2;
    }
  }
}

// ---------------- step (t>=1): XCD-affine fused y_{t-1} + gi + gh + cell ----------------
// Grid 1024 linear blocks, 256 threads (4 waves), 4 blocks/CU.
// Block b: xcd = b&7 (HW round-robin), slot = b>>3; row-group g = xcd*32 + slot/4
// (16 rows, pinned to this XCD every step -> h traffic stays in one L2);
// qb = slot&3 selects 4 of the 16 j-blocks: jb = qb*4 + wid.
// Phase 1 (K=256, A-frags shared): gh 3 tiles/wave + y 1 tile/wave (nt=wid; 4x redundant
// across qb; only qb==0 writes out). X = split2(y) -> LDS. Phase 2: gi from LDS X. Cell.
#define XPAD 72

__global__ __launch_bounds__(256, 4) void gru_step2(
    const bf16_t* __restrict__ Hi0, const bf16_t* __restrict__ Hi1, const bf16_t* __restrict__ Hi2,
    const bf16_t* __restrict__ Wh0, const bf16_t* __restrict__ Wh1,
    const bf16_t* __restrict__ Wi0, const bf16_t* __restrict__ Wi1,
    const bf16_t* __restrict__ Ws0, const bf16_t* __restrict__ Ws1,
    const float* __restrict__ b_ih, const float* __restrict__ b_hh,
    const float* __restrict__ b_lin,
    bf16_t* __restrict__ Ho0, bf16_t* __restrict__ Ho1, bf16_t* __restrict__ Ho2,
    float* __restrict__ yout)  // out + (t-1)*BATCH*64
{
  __shared__ short xl[2 * 16 * XPAD];  // [plane][row][col(padded)]

  const int bid = blockIdx.x;
  const int xcd = bid & 7;
  const int slot = bid >> 3;
  const int g = xcd * 32 + (slot >> 2);  // row-group [0,256)
  const int qb = slot & 3;               // j-quarter [0,4)
  const int wid = threadIdx.x >> 6;
  const int l = threadIdx.x & 63;
  const int lr = l & 15;
  const int lq = l >> 4;
  const int mw = g * 16;
  const int jb = qb * 4 + wid;
  const int j = jb * 16 + lr;

  // ---- phase 1: K=256 loop, shared A-frags: gh (3 gate tiles) + y (nt = wid)
  f32x4 gM[3], gC[3], yM, yC;
#pragma unroll
  for (int gg = 0; gg < 3; ++gg) {
    gM[gg] = (f32x4){0.f, 0.f, 0.f, 0.f};
    gC[gg] = (f32x4){0.f, 0.f, 0.f, 0.f};
  }
  yM = (f32x4){0.f, 0.f, 0.f, 0.f};
  yC = (f32x4){0.f, 0.f, 0.f, 0.f};

  for (int kk = 0; kk < HSZ; kk += 32) {
    size_t ao = (size_t)(mw + lr) * HSZ + kk + lq * 8;
    short8 a0 = *reinterpret_cast<const short8*>(Hi0 + ao);
    short8 a1 = *reinterpret_cast<const short8*>(Hi1 + ao);
#pragma unroll
    for (int gg = 0; gg < 3; ++gg) {
      size_t bo = (size_t)(gg * HSZ + j) * HSZ + kk + lq * 8;
      short8 b0 = *reinterpret_cast<const short8*>(Wh0 + bo);
      short8 b1 = *reinterpret_cast<const short8*>(Wh1 + bo);
      gC[gg] = __builtin_amdgcn_mfma_f32_16x16x32_bf16(a0, b1, gC[gg], 0, 0, 0);
      gC[gg] = __builtin_amdgcn_mfma_f32_16x16x32_bf16(a1, b0, gC[gg], 0, 0, 0);
      gM[gg] = __builtin_amdgcn_mfma_f32_16x16x32_bf16(a0, b0, gM[gg], 0, 0, 0);
    }
    {
      size_t bo = (size_t)(wid * 16 + lr) * HSZ + kk + lq * 8;
      short8 b0 = *reinterpret_cast<const short8*>(Ws0 + bo);
      short8 b1 = *reinterpret_cast<const short8*>(Ws1 + bo);
      yC = __builtin_amdgcn_mfma_f32_16x16x32_bf16(a0, b1, yC, 0, 0, 0);
      yC = __builtin_amdgcn_mfma_f32_16x16x32_bf16(a1, b0, yC, 0, 0, 0);
      yM = __builtin_amdgcn_mfma_f32_16x16x32_bf16(a0, b0, yM, 0, 0, 0);
    }
  }

  // ---- finish y: out (qb==0) + X tile to LDS
  {
    const int col = wid * 16 + lr;
    const float bl = b_lin[col];
#pragma unroll
    for (int q = 0; q < 4; ++q) {
      int lrow = lq * 4 + q;
      float yf = yM[q] + yC[q] + bl;
      if (qb == 0) yout[(size_t)(mw + lrow) * 64 + col] = yf;
      bf16_t p0 = __float2bfloat16(yf);
      bf16_t p1 = __float2bfloat16(yf - __bfloat162float(p0));
      xl[lrow * XPAD + col] = *reinterpret_cast<short*>(&p0);
      xl[16 * XPAD + lrow * XPAD + col] = *reinterpret_cast<short*>(&p1);
    }
  }
  __syncthreads();

  // ---- phase 2: gi = X_lds @ w_ih.T (K=64)
  f32x4 iM[3], iC[3];
#pragma unroll
  for (int gg = 0; gg < 3; ++gg) {
    iM[gg] = (f32x4){0.f, 0.f, 0.f, 0.f};
    iC[gg] = (f32x4){0.f, 0.f, 0.f, 0.f};
  }
#pragma unroll
  for (int kk = 0; kk < ISZ; kk += 32) {
    short8 a0 = *reinterpret_cast<const short8*>(&xl[lr * XPAD + kk + lq * 8]);
    short8 a1 = *reinterpret_cast<const short8*>(&xl[16 * XPAD + lr * XPAD + kk + lq * 8]);
#pragma unroll
    for (int gg = 0; gg < 3; ++gg) {
      size_t bo = (size_t)(gg * HSZ + j) * ISZ + kk + lq * 8;
      short8 b0 = *reinterpret_cast<const short8*>(Wi0 + bo);
      short8 b1 = *reinterpret_cast<const short8*>(Wi1 + bo);
      iC[gg] = __builtin_amdgcn_mfma_f32_16x16x32_bf16(a0, b1, iC[gg], 0, 0, 0);
      iC[gg] = __builtin_amdgcn_mfma_f32_16x16x32_bf16(a1, b0, iC[gg], 0, 0, 0);
      iM[gg] = __builtin_amdgcn_mfma_f32_16x16x32_bf16(a0, b0, iM[gg], 0, 0, 0);
    }
  }

  // ---- cell (R5 formulas, same op order)
  const float brz = b_ih[j] + b_hh[j];
  const float bzz = b_ih[HSZ + j] + b_hh[HSZ + j];
  const float bin = b_ih[2 * HSZ + j];
  const float bhn = b_hh[2 * HSZ + j];

#pragma unroll
  for (int q = 0; q < 4; ++q) {
    int b = mw + lq * 4 + q;  // C/D: row=(lane>>4)*4+reg, col=lane&15
    float rpre = iM[0][q] + iC[0][q] + gM[0][q] + gC[0][q] + brz;
    float zpre = iM[1][q] + iC[1][q] + gM[1][q] + gC[1][q] + bzz;
    float inn  = iM[2][q] + iC[2][q] + bin;
    float hnn  = gM[2][q] + gC[2][q] + bhn;
    float r = sigm(rpre);
    float z = sigm(zpre);
    float n = tanh_fast(inn + r * hnn);
    size_t idx = (size_t)b * HSZ + j;
    double hold = (double)__bfloat162float(Hi0[idx]) + (double)__bfloat162float(Hi1[idx]) +
                  (double)__bfloat162float(Hi2[idx]);
    double hv = (double)((1.f - z) * n) + (double)z * hold;
    bf16_t p0, p1, p2;
    split3(hv, p0, p1, p2);
    Ho0[idx] = p0; Ho1[idx] = p1; Ho2[idx] = p2;
  }
}

// ---------------- final y (out[63]) ----------------
__global__ __launch_bounds__(64) void y_final(
    const bf16_t* __restrict__ H0, const bf16_t* __restrict__ H1,
    const bf16_t* __restrict__ Ws0, const bf16_t* __restrict__ Ws1,
    const float* __restrict__ b_lin,
    float* __restrict__ yout)
{
  const int rg = blockIdx.x >> 2;
  const int nt = blockIdx.x & 3;
  const int mw = rg * 16;
  const int l = threadIdx.x;
  const int lr = l & 15;
  const int lq = l >> 4;

  f32x4 aM = (f32x4){0.f, 0.f, 0.f, 0.f};
  f32x4 aC = (f32x4){0.f, 0.f, 0.f, 0.f};
#pragma unroll 2
  for (int kk = 0; kk < HSZ; kk += 32) {
    size_t ao = (size_t)(mw + lr) * HSZ + kk + lq * 8;
    short8 a0 = *reinterpret_cast<const short8*>(H0 + ao);
    short8 a1 = *reinterpret_cast<const short8*>(H1 + ao);
    size_t bo = (size_t)(nt * 16 + lr) * HSZ + kk + lq * 8;
    short8 b0 = *reinterpret_cast<const short8*>(Ws0 + bo);
    short8 b1 = *reinterpret_cast<const short8*>(Ws1 + bo);
    aC = __builtin_amdgcn_mfma_f32_16x16x32_bf16(a0, b1, aC, 0, 0, 0);
    aC = __builtin_amdgcn_mfma_f32_16x16x32_bf16(a1, b0, aC, 0, 0, 0);
    aM = __builtin_amdgcn_mfma_f32_16x16x32_bf16(a0, b0, aM, 0, 0, 0);
  }
  int o = nt * 16 + lr;
  float bl = b_lin[o];
#pragma unroll
  for (int q = 0; q < 4; ++q)
    yout[(size_t)(mw + lq * 4 + q) * 64 + o] = aM[q] + aC[q] + bl;
}

// ---------------- BatchNorm: two-stage stats + normalize ----------------
__global__ __launch_bounds__(256) void bn_part(const float* __restrict__ Y,
                                               double* __restrict__ psum,
                                               double* __restrict__ psum2)
{
  int t = blockIdx.x;
  int chunk = blockIdx.y;
  int o = threadIdx.x & 63, rg = threadIdx.x >> 6;
  const float* Yt = Y + (size_t)t * BATCH * 64;
  int b0 = chunk * 256;
  double s = 0.0, s2 = 0.0;
  for (int b = b0 + rg; b < b0 + 256; b += 4) {
    double v = (double)Yt[(size_t)b * 64 + o];
    s += v;
    s2 += v * v;
  }
  __shared__ double ls[4][64], ls2[4][64];
  ls[rg][o] = s;
  ls2[rg][o] = s2;
  __syncthreads();
  if (rg == 0) {
    s = ls[0][o] + ls[1][o] + ls[2][o] + ls[3][o];
    s2 = ls2[0][o] + ls2[1][o] + ls2[2][o] + ls2[3][o];
    size_t pi = ((size_t)t * 16 + chunk) * 64 + o;
    psum[pi] = s;
    psum2[pi] = s2;
  }
}

__global__ __launch_bounds__(64) void bn_final(const double* __restrict__ psum,
                                               const double* __restrict__ psum2,
                                               float* __restrict__ mean,
                                               float* __restrict__ istd)
{
  int t = blockIdx.x;
  int o = threadIdx.x;
  double s = 0.0, s2 = 0.0;
  for (int c = 0; c < 16; ++c) {
    size_t pi = ((size_t)t * 16 + c) * 64 + o;
    s += psum[pi];
    s2 += psum2[pi];
  }
  double m = s * (1.0 / BATCH);
  double var = s2 * (1.0 / BATCH) - m * m;
  mean[t * 64 + o] = (float)m;
  istd[t * 64 + o] = (float)(1.0 / sqrt(var + 1e-5));
}

__global__ __launch_bounds__(256) void bn_norm(float* __restrict__ Y,
                                               const float* __restrict__ mean,
                                               const float* __restrict__ istd, int n4)
{
  for (int i = blockIdx.x * 256 + threadIdx.x; i < n4; i += gridDim.x * 256) {
    f32x4 v = reinterpret_cast<f32x4*>(Y)[i];
    int base = i * 4;
    int o = base & 63;
    int t = base >> 18;  // / (BATCH*64)
    const float* mr = mean + t * 64;
    const float* ir = istd + t * 64;
#pragma unroll
    for (int e = 0; e < 4; ++e) v[e] = (v[e] - mr[o + e]) * ir[o + e];
    reinterpret_cast<f32x4*>(Y)[i] = v;
  }
}

extern "C" void kernel_launch(void* const* d_in, const int* in_sizes, int n_in,
                              void* d_out, int out_size, void* d_ws, size_t ws_size,
                              hipStream_t stream)
{
  const float* inputs = (const float*)d_in[0];
  const float* w_ih = (const float*)d_in[1];
  const float* w_hh = (const float*)d_in[2];
  const float* b_ih = (const float*)d_in[3];
  const float* b_hh = (const float*)d_in[4];
  const float* w_lin = (const float*)d_in[5];
  const float* b_lin = (const float*)d_in[6];
  const float* u_sn = (const float*)d_in[7];
  float* out = (float*)d_out;

  const size_t BH = (size_t)BATCH * HSZ;
  const size_t BI = (size_t)BATCH * ISZ;

  char* ws = (char*)d_ws;
  size_t off = 0;
  auto alloc = [&](size_t bytes) -> void* {
    void* p = ws + off;
    off += (bytes + 255) & ~(size_t)255;
    return p;
  };
  double* w_sn_f64 = (double*)alloc((size_t)ISZ * HSZ * 8);
  bf16_t* Wi0 = (bf16_t*)alloc((size_t)3 * HSZ * ISZ * 2);
  bf16_t* Wi1 = (bf16_t*)alloc((size_t)3 * HSZ * ISZ * 2);
  bf16_t* Wh0 = (bf16_t*)alloc((size_t)3 * HSZ * HSZ * 2);
  bf16_t* Wh1 = (bf16_t*)alloc((size_t)3 * HSZ * HSZ * 2);
  bf16_t* Ws0 = (bf16_t*)alloc((size_t)ISZ * HSZ * 2);
  bf16_t* Ws1 = (bf16_t*)alloc((size_t)ISZ * HSZ * 2);
  bf16_t* X0 = (bf16_t*)alloc(BI * 2);
  bf16_t* X1 = (bf16_t*)alloc(BI * 2);
  bf16_t* HA0 = (bf16_t*)alloc(BH * 2);
  bf16_t* HA1 = (bf16_t*)alloc(BH * 2);
  bf16_t* HA2 = (bf16_t*)alloc(BH * 2);
  bf16_t* HB0 = (bf16_t*)alloc(BH * 2);
  bf16_t* HB1 = (bf16_t*)alloc(BH * 2);
  bf16_t* HB2 = (bf16_t*)alloc(BH * 2);
  double* psum = (double*)alloc((size_t)TSZ * 16 * 64 * 8);
  double* psum2 = (double*)alloc((size_t)TSZ * 16 * 64 * 8);
  float* meanb = (float*)alloc(TSZ * 64 * 4);
  float* istdb = (float*)alloc(TSZ * 64 * 4);
  if (off > ws_size) return;

  prep_sn<<<1, 256, 0, stream>>>(w_lin, u_sn, w_sn_f64);
  split2_f32<<<(3 * HSZ * ISZ + 255) / 256, 256, 0, stream>>>(w_ih, Wi0, Wi1, 3 * HSZ * ISZ);
  split2_f32<<<(3 * HSZ * HSZ + 255) / 256, 256, 0, stream>>>(w_hh, Wh0, Wh1, 3 * HSZ * HSZ);
  split2_f64<<<(ISZ * HSZ + 255) / 256, 256, 0, stream>>>(w_sn_f64, Ws0, Ws1, ISZ * HSZ);
  split2_f32<<<((int)BI + 255) / 256, 256, 0, stream>>>(inputs, X0, X1, (int)BI);

  // t = 0
  gru_first<<<dim3(BATCH / 128, 16), 256, 0, stream>>>(X0, X1, Wi0, Wi1, b_ih, b_hh,
                                                       HA0, HA1, HA2);

  bf16_t *Hin0 = HA0, *Hin1 = HA1, *Hin2 = HA2;
  bf16_t *Hout0 = HB0, *Hout1 = HB1, *Hout2 = HB2;
  for (int t = 1; t < TSZ; ++t) {
    gru_step2<<<1024, 256, 0, stream>>>(
        Hin0, Hin1, Hin2, Wh0, Wh1, Wi0, Wi1, Ws0, Ws1,
        b_ih, b_hh, b_lin, Hout0, Hout1, Hout2,
        out + (size_t)(t - 1) * BATCH * 64);
    bf16_t* tm;
    tm = Hin0; Hin0 = Hout0; Hout0 = tm;
    tm = Hin1; Hin1 = Hout1; Hout1 = tm;
    tm = Hin2; Hin2 = Hout2; Hout2 = tm;
  }
  y_final<<<1024, 64, 0, stream>>>(Hin0, Hin1, Ws0, Ws1, b_lin,
                                   out + (size_t)(TSZ - 1) * BATCH * 64);

  bn_part<<<dim3(TSZ, 16), 256, 0, stream>>>(out, psum, psum2);
  bn_final<<<TSZ, 64, 0, stream>>>(psum, psum2, meanb, istdb);
  bn_norm<<<2048, 256, 0, stream>>>(out, meanb, istdb, TSZ * BATCH * 64 / 4);
}

// Round 10
// 2878.514 us; speedup vs baseline: 5.3356x; 1.0128x over previous
//
#include <hip/hip_runtime.h>
#include <hip/hip_bf16.h>

// Session rules (hard-won):
// R6: grid.sync() ~125us on MI355X -- never persistent-coop for a tight recurrence.
// R7: folding w_ih@w_sn into the recurrence fails numerically (0.139, 3x repro).
//     Only bit-equivalent-to-R5 transformations.
// R8/R9: L2 is written-back+invalidated at EVERY kernel boundary (8 non-coherent L2s
//     must be made coherent for the next dispatch) -> ~7.3MB/step compulsory L3 traffic;
//     XCD-affine mapping cannot create cross-kernel L2 reuse.
// R9: __launch_bounds__(256,4) -> VGPR=52 -> zero load pipelining -> latency-bound 48us.
// R10: ILP > TLP: preload A-frags + hold early, full K unroll, no occupancy clamp.

typedef __attribute__((ext_vector_type(8))) short short8;
typedef __attribute__((ext_vector_type(4))) float f32x4;
typedef __hip_bfloat16 bf16_t;

#define BATCH 4096
#define ISZ 64
#define HSZ 256
#define TSZ 64

__device__ __forceinline__ float sigm(float x) { return 1.f / (1.f + __expf(-x)); }
__device__ __forceinline__ float tanh_fast(float x) { return 1.f - 2.f / (1.f + __expf(2.f * x)); }

__device__ __forceinline__ void split3(double x, bf16_t& p0, bf16_t& p1, bf16_t& p2) {
  p0 = __float2bfloat16((float)x);
  double r1 = x - (double)__bfloat162float(p0);
  p1 = __float2bfloat16((float)r1);
  double r2 = r1 - (double)__bfloat162float(p1);
  p2 = __float2bfloat16((float)r2);
}

// ---------------- spectral norm prep, fp64 (1 block) ----------------
__global__ __launch_bounds__(256) void prep_sn(
    const float* __restrict__ w_lin, const float* __restrict__ u_sn,
    double* __restrict__ w_sn_f64)
{
  __shared__ double v[HSZ];
  __shared__ double red[256];
  __shared__ double Wv[ISZ];
  int t = threadIdx.x;
  double s = 0.0;
  for (int i = 0; i < ISZ; ++i) s += (double)w_lin[i * HSZ + t] * (double)u_sn[i];
  red[t] = s * s;
  __syncthreads();
  for (int off = 128; off > 0; off >>= 1) { if (t < off) red[t] += red[t + off]; __syncthreads(); }
  double nv = sqrt(red[0]);
  v[t] = s / (nv + 1e-12);
  __syncthreads();
  {
    int i = t >> 2, p = t & 3;
    double ps = 0.0;
    for (int k = p * 64; k < p * 64 + 64; ++k) ps += (double)w_lin[i * HSZ + k] * v[k];
    red[t] = ps;
    __syncthreads();
    if ((t & 3) == 0) Wv[i] = red[t] + red[t + 1] + red[t + 2] + red[t + 3];
    __syncthreads();
  }
  red[t] = (t < ISZ) ? Wv[t] * Wv[t] : 0.0;
  __syncthreads();
  for (int off = 128; off > 0; off >>= 1) { if (t < off) red[t] += red[t + off]; __syncthreads(); }
  double nw = sqrt(red[0]);
  double sigma = red[0] / (nw + 1e-12);  // u.(Wv), u = Wv/(|Wv|+eps)
  double inv_sigma = 1.0 / sigma;
  for (int idx = t; idx < ISZ * HSZ; idx += 256)
    w_sn_f64[idx] = (double)w_lin[idx] * inv_sigma;
}

// ---------------- 2-plane split casts ----------------
__global__ __launch_bounds__(256) void split2_f32(
    const float* __restrict__ x, bf16_t* __restrict__ p0, bf16_t* __restrict__ p1, int n)
{
  int i = blockIdx.x * 256 + threadIdx.x;
  if (i < n) {
    float v = x[i];
    bf16_t a = __float2bfloat16(v);
    p0[i] = a;
    p1[i] = __float2bfloat16(v - __bfloat162float(a));
  }
}

__global__ __launch_bounds__(256) void split2_f64(
    const double* __restrict__ x, bf16_t* __restrict__ p0, bf16_t* __restrict__ p1, int n)
{
  int i = blockIdx.x * 256 + threadIdx.x;
  if (i < n) {
    double v = x[i];
    bf16_t a = __float2bfloat16((float)v);
    p0[i] = a;
    p1[i] = __float2bfloat16((float)(v - (double)__bfloat162float(a)));
  }
}

// ---------------- t=0 kernel (R5 gru_gates<true>, unchanged) ----------------
__global__ __launch_bounds__(256) void gru_first(
    const bf16_t* __restrict__ X0, const bf16_t* __restrict__ X1,
    const bf16_t* __restrict__ Wi0, const bf16_t* __restrict__ Wi1,
    const float* __restrict__ b_ih, const float* __restrict__ b_hh,
    bf16_t* __restrict__ O0, bf16_t* __restrict__ O1, bf16_t* __restrict__ O2)
{
  const int jb = blockIdx.y;
  const int mw = blockIdx.x * 128 + (threadIdx.x >> 6) * 32;
  const int l = threadIdx.x & 63;
  const int lr = l & 15;
  const int lq = l >> 4;
  const int j = jb * 16 + lr;

  f32x4 accM[2][3], accC[2][3];
#pragma unroll
  for (int mt = 0; mt < 2; ++mt)
#pragma unroll
    for (int g = 0; g < 3; ++g) {
      accM[mt][g] = (f32x4){0.f, 0.f, 0.f, 0.f};
      accC[mt][g] = (f32x4){0.f, 0.f, 0.f, 0.f};
    }

#pragma unroll
  for (int kk = 0; kk < ISZ; kk += 32) {
    short8 a0[2], a1[2];
#pragma unroll
    for (int mt = 0; mt < 2; ++mt) {
      size_t ao = (size_t)(mw + mt * 16 + lr) * ISZ + kk + lq * 8;
      a0[mt] = *reinterpret_cast<const short8*>(X0 + ao);
      a1[mt] = *reinterpret_cast<const short8*>(X1 + ao);
    }
#pragma unroll
    for (int g = 0; g < 3; ++g) {
      size_t bo = (size_t)(g * HSZ + jb * 16 + lr) * ISZ + kk + lq * 8;
      short8 b0 = *reinterpret_cast<const short8*>(Wi0 + bo);
      short8 b1 = *reinterpret_cast<const short8*>(Wi1 + bo);
#pragma unroll
      for (int mt = 0; mt < 2; ++mt) {
        accC[mt][g] = __builtin_amdgcn_mfma_f32_16x16x32_bf16(a0[mt], b1, accC[mt][g], 0, 0, 0);
        accC[mt][g] = __builtin_amdgcn_mfma_f32_16x16x32_bf16(a1[mt], b0, accC[mt][g], 0, 0, 0);
        accM[mt][g] = __builtin_amdgcn_mfma_f32_16x16x32_bf16(a0[mt], b0, accM[mt][g], 0, 0, 0);
      }
    }
  }

  const float brz = b_ih[j] + b_hh[j];
  const float bzz = b_ih[HSZ + j] + b_hh[HSZ + j];
  const float bin = b_ih[2 * HSZ + j];
  const float bhn = b_hh[2 * HSZ + j];

#pragma unroll
  for (int mt = 0; mt < 2; ++mt) {
#pragma unroll
    for (int q = 0; q < 4; ++q) {
      int b = mw + mt * 16 + lq * 4 + q;
      float r = sigm(accM[mt][0][q] + accC[mt][0][q] + brz);
      float z = sigm(accM[mt][1][q] + accC[mt][1][q] + bzz);
      float n = tanh_fast(accM[mt][2][q] + accC[mt][2][q] + bin + r * bhn);
      double hv = (double)((1.f - z) * n);
      size_t idx = (size_t)b * HSZ + j;
      bf16_t p0, p1, p2;
      split3(hv, p0, p1, p2);
      O0[idx] = p0; O1[idx] = p1; O2[idx] = p2;
    }
  }
}

// ---------------- step (t>=1): XCD-affine fused y_{t-1} + gi + gh + cell ----------------
// Grid 1024 linear blocks, 256 threads (4 waves). Block b: xcd=b&7, slot=b>>3;
// row-group g = xcd*32 + slot/4 (16 rows); qb = slot&3; wave jb = qb*4+wid.
// R10: A-frags (full K) + hold preloaded at kernel start; K-loop fully unrolled;
// no occupancy clamp -> compiler pipelines B-loads. Math identical to R9.
#define XPAD 72

__global__ __launch_bounds__(256) void gru_step2(
    const bf16_t* __restrict__ Hi0, const bf16_t* __restrict__ Hi1, const bf16_t* __restrict__ Hi2,
    const bf16_t* __restrict__ Wh0, const bf16_t* __restrict__ Wh1,
    const bf16_t* __restrict__ Wi0, const bf16_t* __restrict__ Wi1,
    const bf16_t* __restrict__ Ws0, const bf16_t* __restrict__ Ws1,
    const float* __restrict__ b_ih, const float* __restrict__ b_hh,
    const float* __restrict__ b_lin,
    bf16_t* __restrict__ Ho0, bf16_t* __restrict__ Ho1, bf16_t* __restrict__ Ho2,
    float* __restrict__ yout)  // out + (t-1)*BATCH*64
{
  __shared__ short xl[2 * 16 * XPAD];  // [plane][row][col(padded)]

  const int bid = blockIdx.x;
  const int xcd = bid & 7;
  const int slot = bid >> 3;
  const int g = xcd * 32 + (slot >> 2);  // row-group [0,256)
  const int qb = slot & 3;               // j-quarter [0,4)
  const int wid = threadIdx.x >> 6;
  const int l = threadIdx.x & 63;
  const int lr = l & 15;
  const int lq = l >> 4;
  const int mw = g * 16;
  const int jb = qb * 4 + wid;
  const int j = jb * 16 + lr;

  // ---- preload hold (consumed only in epilogue; issue loads first)
  double hold_[4];
#pragma unroll
  for (int q = 0; q < 4; ++q) {
    size_t idx = (size_t)(mw + lq * 4 + q) * HSZ + j;
    hold_[q] = (double)__bfloat162float(Hi0[idx]) + (double)__bfloat162float(Hi1[idx]) +
               (double)__bfloat162float(Hi2[idx]);
  }

  // ---- preload ALL A-fragments (K=256: 8 chunks x 2 planes = 64 VGPR)
  short8 a0v[8], a1v[8];
#pragma unroll
  for (int c = 0; c < 8; ++c) {
    size_t ao = (size_t)(mw + lr) * HSZ + c * 32 + lq * 8;
    a0v[c] = *reinterpret_cast<const short8*>(Hi0 + ao);
    a1v[c] = *reinterpret_cast<const short8*>(Hi1 + ao);
  }

  // ---- phase 1: K=256 fully unrolled; gh (3 gate tiles) + y (nt = wid)
  f32x4 gM[3], gC[3], yM, yC;
#pragma unroll
  for (int gg = 0; gg < 3; ++gg) {
    gM[gg] = (f32x4){0.f, 0.f, 0.f, 0.f};
    gC[gg] = (f32x4){0.f, 0.f, 0.f, 0.f};
  }
  yM = (f32x4){0.f, 0.f, 0.f, 0.f};
  yC = (f32x4){0.f, 0.f, 0.f, 0.f};

#pragma unroll
  for (int c = 0; c < 8; ++c) {
    const int kk = c * 32;
#pragma unroll
    for (int gg = 0; gg < 3; ++gg) {
      size_t bo = (size_t)(gg * HSZ + j) * HSZ + kk + lq * 8;
      short8 b0 = *reinterpret_cast<const short8*>(Wh0 + bo);
      short8 b1 = *reinterpret_cast<const short8*>(Wh1 + bo);
      gC[gg] = __builtin_amdgcn_mfma_f32_16x16x32_bf16(a0v[c], b1, gC[gg], 0, 0, 0);
      gC[gg] = __builtin_amdgcn_mfma_f32_16x16x32_bf16(a1v[c], b0, gC[gg], 0, 0, 0);
      gM[gg] = __builtin_amdgcn_mfma_f32_16x16x32_bf16(a0v[c], b0, gM[gg], 0, 0, 0);
    }
    {
      size_t bo = (size_t)(wid * 16 + lr) * HSZ + kk + lq * 8;
      short8 b0 = *reinterpret_cast<const short8*>(Ws0 + bo);
      short8 b1 = *reinterpret_cast<const short8*>(Ws1 + bo);
      yC = __builtin_amdgcn_mfma_f32_16x16x32_bf16(a0v[c], b1, yC, 0, 0, 0);
      yC = __builtin_amdgcn_mfma_f32_16x16x32_bf16(a1v[c], b0, yC, 0, 0, 0);
      yM = __builtin_amdgcn_mfma_f32_16x16x32_bf16(a0v[c], b0, yM, 0, 0, 0);
    }
  }

  // ---- finish y: out (qb==0) + X tile to LDS
  {
    const int col = wid * 16 + lr;
    const float bl = b_lin[col];
#pragma unroll
    for (int q = 0; q < 4; ++q) {
      int lrow = lq * 4 + q;
      float yf = yM[q] + yC[q] + bl;
      if (qb == 0) yout[(size_t)(mw + lrow) * 64 + col] = yf;
      bf16_t p0 = __float2bfloat16(yf);
      bf16_t p1 = __float2bfloat16(yf - __bfloat162float(p0));
      xl[lrow * XPAD + col] = *reinterpret_cast<short*>(&p0);
      xl[16 * XPAD + lrow * XPAD + col] = *reinterpret_cast<short*>(&p1);
    }
  }
  __syncthreads();

  // ---- phase 2: gi = X_lds @ w_ih.T (K=64)
  f32x4 iM[3], iC[3];
#pragma unroll
  for (int gg = 0; gg < 3; ++gg) {
    iM[gg] = (f32x4){0.f, 0.f, 0.f, 0.f};
    iC[gg] = (f32x4){0.f, 0.f, 0.f, 0.f};
  }
#pragma unroll
  for (int kk = 0; kk < ISZ; kk += 32) {
    short8 a0 = *reinterpret_cast<const short8*>(&xl[lr * XPAD + kk + lq * 8]);
    short8 a1 = *reinterpret_cast<const short8*>(&xl[16 * XPAD + lr * XPAD + kk + lq * 8]);
#pragma unroll
    for (int gg = 0; gg < 3; ++gg) {
      size_t bo = (size_t)(gg * HSZ + j) * ISZ + kk + lq * 8;
      short8 b0 = *reinterpret_cast<const short8*>(Wi0 + bo);
      short8 b1 = *reinterpret_cast<const short8*>(Wi1 + bo);
      iC[gg] = __builtin_amdgcn_mfma_f32_16x16x32_bf16(a0, b1, iC[gg], 0, 0, 0);
      iC[gg] = __builtin_amdgcn_mfma_f32_16x16x32_bf16(a1, b0, iC[gg], 0, 0, 0);
      iM[gg] = __builtin_amdgcn_mfma_f32_16x16x32_bf16(a0, b0, iM[gg], 0, 0, 0);
    }
  }

  // ---- cell (identical op order)
  const float brz = b_ih[j] + b_hh[j];
  const float bzz = b_ih[HSZ + j] + b_hh[HSZ + j];
  const float bin = b_ih[2 * HSZ + j];
  const float bhn = b_hh[2 * HSZ + j];

#pragma unroll
  for (int q = 0; q < 4; ++q) {
    int b = mw + lq * 4 + q;  // C/D: row=(lane>>4)*4+reg, col=lane&15
    float rpre = iM[0][q] + iC[0][q] + gM[0][q] + gC[0][q] + brz;
    float zpre = iM[1][q] + iC[1][q] + gM[1][q] + gC[1][q] + bzz;
    float inn  = iM[2][q] + iC[2][q] + bin;
    float hnn  = gM[2][q] + gC[2][q] + bhn;
    float r = sigm(rpre);
    float z = sigm(zpre);
    float n = tanh_fast(inn + r * hnn);
    size_t idx = (size_t)b * HSZ + j;
    double hv = (double)((1.f - z) * n) + (double)z * hold_[q];
    bf16_t p0, p1, p2;
    split3(hv, p0, p1, p2);
    Ho0[idx] = p0; Ho1[idx] = p1; Ho2[idx] = p2;
  }
}

// ---------------- final y (out[63]) ----------------
__global__ __launch_bounds__(64) void y_final(
    const bf16_t* __restrict__ H0, const bf16_t* __restrict__ H1,
    const bf16_t* __restrict__ Ws0, const bf16_t* __restrict__ Ws1,
    const float* __restrict__ b_lin,
    float* __restrict__ yout)
{
  const int rg = blockIdx.x >> 2;
  const int nt = blockIdx.x & 3;
  const int mw = rg * 16;
  const int l = threadIdx.x;
  const int lr = l & 15;
  const int lq = l >> 4;

  f32x4 aM = (f32x4){0.f, 0.f, 0.f, 0.f};
  f32x4 aC = (f32x4){0.f, 0.f, 0.f, 0.f};
#pragma unroll 2
  for (int kk = 0; kk < HSZ; kk += 32) {
    size_t ao = (size_t)(mw + lr) * HSZ + kk + lq * 8;
    short8 a0 = *reinterpret_cast<const short8*>(H0 + ao);
    short8 a1 = *reinterpret_cast<const short8*>(H1 + ao);
    size_t bo = (size_t)(nt * 16 + lr) * HSZ + kk + lq * 8;
    short8 b0 = *reinterpret_cast<const short8*>(Ws0 + bo);
    short8 b1 = *reinterpret_cast<const short8*>(Ws1 + bo);
    aC = __builtin_amdgcn_mfma_f32_16x16x32_bf16(a0, b1, aC, 0, 0, 0);
    aC = __builtin_amdgcn_mfma_f32_16x16x32_bf16(a1, b0, aC, 0, 0, 0);
    aM = __builtin_amdgcn_mfma_f32_16x16x32_bf16(a0, b0, aM, 0, 0, 0);
  }
  int o = nt * 16 + lr;
  float bl = b_lin[o];
#pragma unroll
  for (int q = 0; q < 4; ++q)
    yout[(size_t)(mw + lq * 4 + q) * 64 + o] = aM[q] + aC[q] + bl;
}

// ---------------- BatchNorm: two-stage stats + normalize ----------------
__global__ __launch_bounds__(256) void bn_part(const float* __restrict__ Y,
                                               double* __restrict__ psum,
                                               double* __restrict__ psum2)
{
  int t = blockIdx.x;
  int chunk = blockIdx.y;
  int o = threadIdx.x & 63, rg = threadIdx.x >> 6;
  const float* Yt = Y + (size_t)t * BATCH * 64;
  int b0 = chunk * 256;
  double s = 0.0, s2 = 0.0;
  for (int b = b0 + rg; b < b0 + 256; b += 4) {
    double v = (double)Yt[(size_t)b * 64 + o];
    s += v;
    s2 += v * v;
  }
  __shared__ double ls[4][64], ls2[4][64];
  ls[rg][o] = s;
  ls2[rg][o] = s2;
  __syncthreads();
  if (rg == 0) {
    s = ls[0][o] + ls[1][o] + ls[2][o] + ls[3][o];
    s2 = ls2[0][o] + ls2[1][o] + ls2[2][o] + ls2[3][o];
    size_t pi = ((size_t)t * 16 + chunk) * 64 + o;
    psum[pi] = s;
    psum2[pi] = s2;
  }
}

__global__ __launch_bounds__(64) void bn_final(const double* __restrict__ psum,
                                               const double* __restrict__ psum2,
                                               float* __restrict__ mean,
                                               float* __restrict__ istd)
{
  int t = blockIdx.x;
  int o = threadIdx.x;
  double s = 0.0, s2 = 0.0;
  for (int c = 0; c < 16; ++c) {
    size_t pi = ((size_t)t * 16 + c) * 64 + o;
    s += psum[pi];
    s2 += psum2[pi];
  }
  double m = s * (1.0 / BATCH);
  double var = s2 * (1.0 / BATCH) - m * m;
  mean[t * 64 + o] = (float)m;
  istd[t * 64 + o] = (float)(1.0 / sqrt(var + 1e-5));
}

__global__ __launch_bounds__(256) void bn_norm(float* __restrict__ Y,
                                               const float* __restrict__ mean,
                                               const float* __restrict__ istd, int n4)
{
  for (int i = blockIdx.x * 256 + threadIdx.x; i < n4; i += gridDim.x * 256) {
    f32x4 v = reinterpret_cast<f32x4*>(Y)[i];
    int base = i * 4;
    int o = base & 63;
    int t = base >> 18;  // / (BATCH*64)
    const float* mr = mean + t * 64;
    const float* ir = istd + t * 64;
#pragma unroll
    for (int e = 0; e < 4; ++e) v[e] = (v[e] - mr[o + e]) * ir[o + e];
    reinterpret_cast<f32x4*>(Y)[i] = v;
  }
}

extern "C" void kernel_launch(void* const* d_in, const int* in_sizes, int n_in,
                              void* d_out, int out_size, void* d_ws, size_t ws_size,
                              hipStream_t stream)
{
  const float* inputs = (const float*)d_in[0];
  const float* w_ih = (const float*)d_in[1];
  const float* w_hh = (const float*)d_in[2];
  const float* b_ih = (const float*)d_in[3];
  const float* b_hh = (const float*)d_in[4];
  const float* w_lin = (const float*)d_in[5];
  const float* b_lin = (const float*)d_in[6];
  const float* u_sn = (const float*)d_in[7];
  float* out = (float*)d_out;

  const size_t BH = (size_t)BATCH * HSZ;
  const size_t BI = (size_t)BATCH * ISZ;

  char* ws = (char*)d_ws;
  size_t off = 0;
  auto alloc = [&](size_t bytes) -> void* {
    void* p = ws + off;
    off += (bytes + 255) & ~(size_t)255;
    return p;
  };
  double* w_sn_f64 = (double*)alloc((size_t)ISZ * HSZ * 8);
  bf16_t* Wi0 = (bf16_t*)alloc((size_t)3 * HSZ * ISZ * 2);
  bf16_t* Wi1 = (bf16_t*)alloc((size_t)3 * HSZ * ISZ * 2);
  bf16_t* Wh0 = (bf16_t*)alloc((size_t)3 * HSZ * HSZ * 2);
  bf16_t* Wh1 = (bf16_t*)alloc((size_t)3 * HSZ * HSZ * 2);
  bf16_t* Ws0 = (bf16_t*)alloc((size_t)ISZ * HSZ * 2);
  bf16_t* Ws1 = (bf16_t*)alloc((size_t)ISZ * HSZ * 2);
  bf16_t* X0 = (bf16_t*)alloc(BI * 2);
  bf16_t* X1 = (bf16_t*)alloc(BI * 2);
  bf16_t* HA0 = (bf16_t*)alloc(BH * 2);
  bf16_t* HA1 = (bf16_t*)alloc(BH * 2);
  bf16_t* HA2 = (bf16_t*)alloc(BH * 2);
  bf16_t* HB0 = (bf16_t*)alloc(BH * 2);
  bf16_t* HB1 = (bf16_t*)alloc(BH * 2);
  bf16_t* HB2 = (bf16_t*)alloc(BH * 2);
  double* psum = (double*)alloc((size_t)TSZ * 16 * 64 * 8);
  double* psum2 = (double*)alloc((size_t)TSZ * 16 * 64 * 8);
  float* meanb = (float*)alloc(TSZ * 64 * 4);
  float* istdb = (float*)alloc(TSZ * 64 * 4);
  if (off > ws_size) return;

  prep_sn<<<1, 256, 0, stream>>>(w_lin, u_sn, w_sn_f64);
  split2_f32<<<(3 * HSZ * ISZ + 255) / 256, 256, 0, stream>>>(w_ih, Wi0, Wi1, 3 * HSZ * ISZ);
  split2_f32<<<(3 * HSZ * HSZ + 255) / 256, 256, 0, stream>>>(w_hh, Wh0, Wh1, 3 * HSZ * HSZ);
  split2_f64<<<(ISZ * HSZ + 255) / 256, 256, 0, stream>>>(w_sn_f64, Ws0, Ws1, ISZ * HSZ);
  split2_f32<<<((int)BI + 255) / 256, 256, 0, stream>>>(inputs, X0, X1, (int)BI);

  // t = 0
  gru_first<<<dim3(BATCH / 128, 16), 256, 0, stream>>>(X0, X1, Wi0, Wi1, b_ih, b_hh,
                                                       HA0, HA1, HA2);

  bf16_t *Hin0 = HA0, *Hin1 = HA1, *Hin2 = HA2;
  bf16_t *Hout0 = HB0, *Hout1 = HB1, *Hout2 = HB2;
  for (int t = 1; t < TSZ; ++t) {
    gru_step2<<<1024, 256, 0, stream>>>(
        Hin0, Hin1, Hin2, Wh0, Wh1, Wi0, Wi1, Ws0, Ws1,
        b_ih, b_hh, b_lin, Hout0, Hout1, Hout2,
        out + (size_t)(t - 1) * BATCH * 64);
    bf16_t* tm;
    tm = Hin0; Hin0 = Hout0; Hout0 = tm;
    tm = Hin1; Hin1 = Hout1; Hout1 = tm;
    tm = Hin2; Hin2 = Hout2; Hout2 = tm;
  }
  y_final<<<1024, 64, 0, stream>>>(Hin0, Hin1, Ws0, Ws1, b_lin,
                                   out + (size_t)(TSZ - 1) * BATCH * 64);

  bn_part<<<dim3(TSZ, 16), 256, 0, stream>>>(out, psum, psum2);
  bn_final<<<TSZ, 64, 0, stream>>>(psum, psum2, meanb, istdb);
  bn_norm<<<2048, 256, 0, stream>>>(out, meanb, istdb, TSZ * BATCH * 64 / 4);
}

// Round 11
// 2336.209 us; speedup vs baseline: 6.5741x; 1.2321x over previous
//
#include <hip/hip_runtime.h>
#include <hip/hip_bf16.h>

// Session rules (hard-won):
// R6: grid.sync() ~125us on MI355X -- never persistent-coop for a tight recurrence.
// R7: folding w_ih@w_sn into the recurrence fails numerically (0.139, 3x repro).
//     Only value-preserving transformations of the R5 dataflow.
// R8/R9: L2 is flushed at kernel boundaries -> ~7MB/step compulsory L3 traffic;
//     XCD-affine mapping can't create cross-kernel L2 reuse. Fusion regressed (R8-R10).
// R9: occupancy clamp (min-waves) strangles VGPR -> no load pipelining.
// R10: register-preload defeated -- compiler legally sinks loads (VGPR stayed 60).
// R11: best-known = R5 two-kernel structure. Attack: fp32 h-state (no sub-dword
//     stores/loads, -25% traffic), X planes derived in-register from out[t-1].

typedef __attribute__((ext_vector_type(8))) short short8;
typedef __attribute__((ext_vector_type(4))) float f32x4;
typedef __hip_bfloat16 bf16_t;

#define BATCH 4096
#define ISZ 64
#define HSZ 256
#define TSZ 64

__device__ __forceinline__ float sigm(float x) { return 1.f / (1.f + __expf(-x)); }
__device__ __forceinline__ float tanh_fast(float x) { return 1.f - 2.f / (1.f + __expf(2.f * x)); }

// load 8 consecutive fp32 and split into two bf16 planes (in-register, RNE)
__device__ __forceinline__ void load_cvt(const float* __restrict__ p, short8& a0, short8& a1) {
  f32x4 u = *reinterpret_cast<const f32x4*>(p);
  f32x4 w = *reinterpret_cast<const f32x4*>(p + 4);
  float x[8] = {u[0], u[1], u[2], u[3], w[0], w[1], w[2], w[3]};
#pragma unroll
  for (int e = 0; e < 8; ++e) {
    bf16_t h0 = __float2bfloat16(x[e]);
    a0[e] = *reinterpret_cast<short*>(&h0);
    bf16_t h1 = __float2bfloat16(x[e] - __bfloat162float(h0));
    a1[e] = *reinterpret_cast<short*>(&h1);
  }
}

// ---------------- spectral norm prep, fp64 (1 block) ----------------
__global__ __launch_bounds__(256) void prep_sn(
    const float* __restrict__ w_lin, const float* __restrict__ u_sn,
    double* __restrict__ w_sn_f64)
{
  __shared__ double v[HSZ];
  __shared__ double red[256];
  __shared__ double Wv[ISZ];
  int t = threadIdx.x;
  double s = 0.0;
  for (int i = 0; i < ISZ; ++i) s += (double)w_lin[i * HSZ + t] * (double)u_sn[i];
  red[t] = s * s;
  __syncthreads();
  for (int off = 128; off > 0; off >>= 1) { if (t < off) red[t] += red[t + off]; __syncthreads(); }
  double nv = sqrt(red[0]);
  v[t] = s / (nv + 1e-12);
  __syncthreads();
  {
    int i = t >> 2, p = t & 3;
    double ps = 0.0;
    for (int k = p * 64; k < p * 64 + 64; ++k) ps += (double)w_lin[i * HSZ + k] * v[k];
    red[t] = ps;
    __syncthreads();
    if ((t & 3) == 0) Wv[i] = red[t] + red[t + 1] + red[t + 2] + red[t + 3];
    __syncthreads();
  }
  red[t] = (t < ISZ) ? Wv[t] * Wv[t] : 0.0;
  __syncthreads();
  for (int off = 128; off > 0; off >>= 1) { if (t < off) red[t] += red[t + off]; __syncthreads(); }
  double nw = sqrt(red[0]);
  double sigma = red[0] / (nw + 1e-12);  // u.(Wv), u = Wv/(|Wv|+eps)
  double inv_sigma = 1.0 / sigma;
  for (int idx = t; idx < ISZ * HSZ; idx += 256)
    w_sn_f64[idx] = (double)w_lin[idx] * inv_sigma;
}

// ---------------- 2-plane split casts (weights + t=0 inputs) ----------------
__global__ __launch_bounds__(256) void split2_f32(
    const float* __restrict__ x, bf16_t* __restrict__ p0, bf16_t* __restrict__ p1, int n)
{
  int i = blockIdx.x * 256 + threadIdx.x;
  if (i < n) {
    float v = x[i];
    bf16_t a = __float2bfloat16(v);
    p0[i] = a;
    p1[i] = __float2bfloat16(v - __bfloat162float(a));
  }
}

__global__ __launch_bounds__(256) void split2_f64(
    const double* __restrict__ x, bf16_t* __restrict__ p0, bf16_t* __restrict__ p1, int n)
{
  int i = blockIdx.x * 256 + threadIdx.x;
  if (i < n) {
    double v = x[i];
    bf16_t a = __float2bfloat16((float)v);
    p0[i] = a;
    p1[i] = __float2bfloat16((float)(v - (double)__bfloat162float(a)));
  }
}

// ---------------- t=0: gi from inputs, h1 = (1-z)*n -> fp32 ----------------
__global__ __launch_bounds__(256) void gru_first(
    const bf16_t* __restrict__ X0, const bf16_t* __restrict__ X1,
    const bf16_t* __restrict__ Wi0, const bf16_t* __restrict__ Wi1,
    const float* __restrict__ b_ih, const float* __restrict__ b_hh,
    float* __restrict__ hF)
{
  const int jb = blockIdx.y;
  const int mw = blockIdx.x * 128 + (threadIdx.x >> 6) * 32;
  const int l = threadIdx.x & 63;
  const int lr = l & 15;
  const int lq = l >> 4;
  const int j = jb * 16 + lr;

  f32x4 accM[2][3], accC[2][3];
#pragma unroll
  for (int mt = 0; mt < 2; ++mt)
#pragma unroll
    for (int g = 0; g < 3; ++g) {
      accM[mt][g] = (f32x4){0.f, 0.f, 0.f, 0.f};
      accC[mt][g] = (f32x4){0.f, 0.f, 0.f, 0.f};
    }

#pragma unroll
  for (int kk = 0; kk < ISZ; kk += 32) {
    short8 a0[2], a1[2];
#pragma unroll
    for (int mt = 0; mt < 2; ++mt) {
      size_t ao = (size_t)(mw + mt * 16 + lr) * ISZ + kk + lq * 8;
      a0[mt] = *reinterpret_cast<const short8*>(X0 + ao);
      a1[mt] = *reinterpret_cast<const short8*>(X1 + ao);
    }
#pragma unroll
    for (int g = 0; g < 3; ++g) {
      size_t bo = (size_t)(g * HSZ + jb * 16 + lr) * ISZ + kk + lq * 8;
      short8 b0 = *reinterpret_cast<const short8*>(Wi0 + bo);
      short8 b1 = *reinterpret_cast<const short8*>(Wi1 + bo);
#pragma unroll
      for (int mt = 0; mt < 2; ++mt) {
        accC[mt][g] = __builtin_amdgcn_mfma_f32_16x16x32_bf16(a0[mt], b1, accC[mt][g], 0, 0, 0);
        accC[mt][g] = __builtin_amdgcn_mfma_f32_16x16x32_bf16(a1[mt], b0, accC[mt][g], 0, 0, 0);
        accM[mt][g] = __builtin_amdgcn_mfma_f32_16x16x32_bf16(a0[mt], b0, accM[mt][g], 0, 0, 0);
      }
    }
  }

  const float brz = b_ih[j] + b_hh[j];
  const float bzz = b_ih[HSZ + j] + b_hh[HSZ + j];
  const float bin = b_ih[2 * HSZ + j];
  const float bhn = b_hh[2 * HSZ + j];

#pragma unroll
  for (int mt = 0; mt < 2; ++mt) {
#pragma unroll
    for (int q = 0; q < 4; ++q) {
      int b = mw + mt * 16 + lq * 4 + q;
      float r = sigm(accM[mt][0][q] + accC[mt][0][q] + brz);
      float z = sigm(accM[mt][1][q] + accC[mt][1][q] + bzz);
      float n = tanh_fast(accM[mt][2][q] + accC[mt][2][q] + bin + r * bhn);
      hF[(size_t)b * HSZ + j] = (1.f - z) * n;
    }
  }
}

// ---------------- gates step (t>=1): gi(from y=out[t-1]) + gh(from hF) + cell ----------------
// Grid (BATCH/128, 16); block 256 = 4 waves; wave = 32 rows (2 mt tiles) x 16 j.
// A-operand bf16 planes derived in-register from fp32 (plane0 bit-identical to R5;
// plane1 differs only at 2^-24 class -- proven-insensitive). gi operands bit-identical.
__global__ __launch_bounds__(256) void gru_gates(
    const float* __restrict__ yprev,  // out + (t-1)*BATCH*64
    const float* __restrict__ hF,     // [BATCH, 256] fp32
    const bf16_t* __restrict__ Wi0, const bf16_t* __restrict__ Wi1,
    const bf16_t* __restrict__ Wh0, const bf16_t* __restrict__ Wh1,
    const float* __restrict__ b_ih, const float* __restrict__ b_hh,
    float* __restrict__ hFo)
{
  const int jb = blockIdx.y;
  const int mw = blockIdx.x * 128 + (threadIdx.x >> 6) * 32;
  const int l = threadIdx.x & 63;
  const int lr = l & 15;
  const int lq = l >> 4;
  const int j = jb * 16 + lr;

  // hold: one fp32 load per output element (issue early)
  float hold_[2][4];
#pragma unroll
  for (int mt = 0; mt < 2; ++mt)
#pragma unroll
    for (int q = 0; q < 4; ++q)
      hold_[mt][q] = hF[(size_t)(mw + mt * 16 + lq * 4 + q) * HSZ + j];

  f32x4 accM[2][4], accC[2][4];
#pragma unroll
  for (int mt = 0; mt < 2; ++mt)
#pragma unroll
    for (int g = 0; g < 4; ++g) {
      accM[mt][g] = (f32x4){0.f, 0.f, 0.f, 0.f};
      accC[mt][g] = (f32x4){0.f, 0.f, 0.f, 0.f};
    }

  // ---- gi: x = split2(yprev) @ w_ih.T (K=64); gates 0,1,2 -> cols 0,1,2
#pragma unroll
  for (int kk = 0; kk < ISZ; kk += 32) {
    short8 a0[2], a1[2];
#pragma unroll
    for (int mt = 0; mt < 2; ++mt)
      load_cvt(yprev + (size_t)(mw + mt * 16 + lr) * ISZ + kk + lq * 8, a0[mt], a1[mt]);
#pragma unroll
    for (int g = 0; g < 3; ++g) {
      size_t bo = (size_t)(g * HSZ + jb * 16 + lr) * ISZ + kk + lq * 8;
      short8 b0 = *reinterpret_cast<const short8*>(Wi0 + bo);
      short8 b1 = *reinterpret_cast<const short8*>(Wi1 + bo);
#pragma unroll
      for (int mt = 0; mt < 2; ++mt) {
        accC[mt][g] = __builtin_amdgcn_mfma_f32_16x16x32_bf16(a0[mt], b1, accC[mt][g], 0, 0, 0);
        accC[mt][g] = __builtin_amdgcn_mfma_f32_16x16x32_bf16(a1[mt], b0, accC[mt][g], 0, 0, 0);
        accM[mt][g] = __builtin_amdgcn_mfma_f32_16x16x32_bf16(a0[mt], b0, accM[mt][g], 0, 0, 0);
      }
    }
  }

  // ---- gh: h = split2(hF) @ w_hh.T (K=256); gates 0,1 -> cols 0,1; gate 2 -> col 3
  for (int kk = 0; kk < HSZ; kk += 32) {
    short8 a0[2], a1[2];
#pragma unroll
    for (int mt = 0; mt < 2; ++mt)
      load_cvt(hF + (size_t)(mw + mt * 16 + lr) * HSZ + kk + lq * 8, a0[mt], a1[mt]);
#pragma unroll
    for (int g = 0; g < 3; ++g) {
      const int tgt = (g == 2) ? 3 : g;
      size_t bo = (size_t)(g * HSZ + jb * 16 + lr) * HSZ + kk + lq * 8;
      short8 b0 = *reinterpret_cast<const short8*>(Wh0 + bo);
      short8 b1 = *reinterpret_cast<const short8*>(Wh1 + bo);
#pragma unroll
      for (int mt = 0; mt < 2; ++mt) {
        accC[mt][tgt] = __builtin_amdgcn_mfma_f32_16x16x32_bf16(a0[mt], b1, accC[mt][tgt], 0, 0, 0);
        accC[mt][tgt] = __builtin_amdgcn_mfma_f32_16x16x32_bf16(a1[mt], b0, accC[mt][tgt], 0, 0, 0);
        accM[mt][tgt] = __builtin_amdgcn_mfma_f32_16x16x32_bf16(a0[mt], b0, accM[mt][tgt], 0, 0, 0);
      }
    }
  }

  const float brz = b_ih[j] + b_hh[j];
  const float bzz = b_ih[HSZ + j] + b_hh[HSZ + j];
  const float bin = b_ih[2 * HSZ + j];
  const float bhn = b_hh[2 * HSZ + j];

#pragma unroll
  for (int mt = 0; mt < 2; ++mt) {
#pragma unroll
    for (int q = 0; q < 4; ++q) {
      int b = mw + mt * 16 + lq * 4 + q;  // C/D: row=(lane>>4)*4+reg, col=lane&15
      float rpre = accM[mt][0][q] + accC[mt][0][q] + brz;
      float zpre = accM[mt][1][q] + accC[mt][1][q] + bzz;
      float inn  = accM[mt][2][q] + accC[mt][2][q] + bin;
      float hnn  = accM[mt][3][q] + accC[mt][3][q] + bhn;
      float r = sigm(rpre);
      float z = sigm(zpre);
      float n = tanh_fast(inn + r * hnn);
      double hv = (double)((1.f - z) * n) + (double)z * (double)hold_[mt][q];
      hFo[(size_t)b * HSZ + j] = (float)hv;
    }
  }
}

// ---------------- y_step: out[t] = split2(hF) @ w_sn.T + b_lin ----------------
// Grid BATCH/16 one-wave blocks; wave = 16 rows x 64 cols (4 col tiles).
__global__ __launch_bounds__(64) void y_step(
    const float* __restrict__ hF,
    const bf16_t* __restrict__ Ws0, const bf16_t* __restrict__ Ws1,
    const float* __restrict__ b_lin,
    float* __restrict__ yout)  // out + t*BATCH*64
{
  const int mw = blockIdx.x * 16;
  const int l = threadIdx.x;
  const int lr = l & 15;
  const int lq = l >> 4;

  f32x4 accM[4], accC[4];
#pragma unroll
  for (int nt = 0; nt < 4; ++nt) {
    accM[nt] = (f32x4){0.f, 0.f, 0.f, 0.f};
    accC[nt] = (f32x4){0.f, 0.f, 0.f, 0.f};
  }

  for (int kk = 0; kk < HSZ; kk += 32) {
    short8 a0, a1;
    load_cvt(hF + (size_t)(mw + lr) * HSZ + kk + lq * 8, a0, a1);
#pragma unroll
    for (int nt = 0; nt < 4; ++nt) {
      size_t bo = (size_t)(nt * 16 + lr) * HSZ + kk + lq * 8;
      short8 b0 = *reinterpret_cast<const short8*>(Ws0 + bo);
      short8 b1 = *reinterpret_cast<const short8*>(Ws1 + bo);
      accC[nt] = __builtin_amdgcn_mfma_f32_16x16x32_bf16(a0, b1, accC[nt], 0, 0, 0);
      accC[nt] = __builtin_amdgcn_mfma_f32_16x16x32_bf16(a1, b0, accC[nt], 0, 0, 0);
      accM[nt] = __builtin_amdgcn_mfma_f32_16x16x32_bf16(a0, b0, accM[nt], 0, 0, 0);
    }
  }

#pragma unroll
  for (int q = 0; q < 4; ++q) {
    size_t row = mw + lq * 4 + q;
#pragma unroll
    for (int nt = 0; nt < 4; ++nt) {
      int o = nt * 16 + lr;
      yout[row * 64 + o] = accM[nt][q] + accC[nt][q] + b_lin[o];
    }
  }
}

// ---------------- BatchNorm: two-stage stats + normalize ----------------
__global__ __launch_bounds__(256) void bn_part(const float* __restrict__ Y,
                                               double* __restrict__ psum,
                                               double* __restrict__ psum2)
{
  int t = blockIdx.x;
  int chunk = blockIdx.y;
  int o = threadIdx.x & 63, rg = threadIdx.x >> 6;
  const float* Yt = Y + (size_t)t * BATCH * 64;
  int b0 = chunk * 256;
  double s = 0.0, s2 = 0.0;
  for (int b = b0 + rg; b < b0 + 256; b += 4) {
    double v = (double)Yt[(size_t)b * 64 + o];
    s += v;
    s2 += v * v;
  }
  __shared__ double ls[4][64], ls2[4][64];
  ls[rg][o] = s;
  ls2[rg][o] = s2;
  __syncthreads();
  if (rg == 0) {
    s = ls[0][o] + ls[1][o] + ls[2][o] + ls[3][o];
    s2 = ls2[0][o] + ls2[1][o] + ls2[2][o] + ls2[3][o];
    size_t pi = ((size_t)t * 16 + chunk) * 64 + o;
    psum[pi] = s;
    psum2[pi] = s2;
  }
}

__global__ __launch_bounds__(64) void bn_final(const double* __restrict__ psum,
                                               const double* __restrict__ psum2,
                                               float* __restrict__ mean,
                                               float* __restrict__ istd)
{
  int t = blockIdx.x;
  int o = threadIdx.x;
  double s = 0.0, s2 = 0.0;
  for (int c = 0; c < 16; ++c) {
    size_t pi = ((size_t)t * 16 + c) * 64 + o;
    s += psum[pi];
    s2 += psum2[pi];
  }
  double m = s * (1.0 / BATCH);
  double var = s2 * (1.0 / BATCH) - m * m;
  mean[t * 64 + o] = (float)m;
  istd[t * 64 + o] = (float)(1.0 / sqrt(var + 1e-5));
}

__global__ __launch_bounds__(256) void bn_norm(float* __restrict__ Y,
                                               const float* __restrict__ mean,
                                               const float* __restrict__ istd, int n4)
{
  for (int i = blockIdx.x * 256 + threadIdx.x; i < n4; i += gridDim.x * 256) {
    f32x4 v = reinterpret_cast<f32x4*>(Y)[i];
    int base = i * 4;
    int o = base & 63;
    int t = base >> 18;  // / (BATCH*64)
    const float* mr = mean + t * 64;
    const float* ir = istd + t * 64;
#pragma unroll
    for (int e = 0; e < 4; ++e) v[e] = (v[e] - mr[o + e]) * ir[o + e];
    reinterpret_cast<f32x4*>(Y)[i] = v;
  }
}

extern "C" void kernel_launch(void* const* d_in, const int* in_sizes, int n_in,
                              void* d_out, int out_size, void* d_ws, size_t ws_size,
                              hipStream_t stream)
{
  const float* inputs = (const float*)d_in[0];
  const float* w_ih = (const float*)d_in[1];
  const float* w_hh = (const float*)d_in[2];
  const float* b_ih = (const float*)d_in[3];
  const float* b_hh = (const float*)d_in[4];
  const float* w_lin = (const float*)d_in[5];
  const float* b_lin = (const float*)d_in[6];
  const float* u_sn = (const float*)d_in[7];
  float* out = (float*)d_out;

  const size_t BH = (size_t)BATCH * HSZ;
  const size_t BI = (size_t)BATCH * ISZ;

  char* ws = (char*)d_ws;
  size_t off = 0;
  auto alloc = [&](size_t bytes) -> void* {
    void* p = ws + off;
    off += (bytes + 255) & ~(size_t)255;
    return p;
  };
  double* w_sn_f64 = (double*)alloc((size_t)ISZ * HSZ * 8);
  bf16_t* Wi0 = (bf16_t*)alloc((size_t)3 * HSZ * ISZ * 2);
  bf16_t* Wi1 = (bf16_t*)alloc((size_t)3 * HSZ * ISZ * 2);
  bf16_t* Wh0 = (bf16_t*)alloc((size_t)3 * HSZ * HSZ * 2);
  bf16_t* Wh1 = (bf16_t*)alloc((size_t)3 * HSZ * HSZ * 2);
  bf16_t* Ws0 = (bf16_t*)alloc((size_t)ISZ * HSZ * 2);
  bf16_t* Ws1 = (bf16_t*)alloc((size_t)ISZ * HSZ * 2);
  bf16_t* X0 = (bf16_t*)alloc(BI * 2);
  bf16_t* X1 = (bf16_t*)alloc(BI * 2);
  float* hFA = (float*)alloc(BH * 4);
  float* hFB = (float*)alloc(BH * 4);
  double* psum = (double*)alloc((size_t)TSZ * 16 * 64 * 8);
  double* psum2 = (double*)alloc((size_t)TSZ * 16 * 64 * 8);
  float* meanb = (float*)alloc(TSZ * 64 * 4);
  float* istdb = (float*)alloc(TSZ * 64 * 4);
  if (off > ws_size) return;

  prep_sn<<<1, 256, 0, stream>>>(w_lin, u_sn, w_sn_f64);
  split2_f32<<<(3 * HSZ * ISZ + 255) / 256, 256, 0, stream>>>(w_ih, Wi0, Wi1, 3 * HSZ * ISZ);
  split2_f32<<<(3 * HSZ * HSZ + 255) / 256, 256, 0, stream>>>(w_hh, Wh0, Wh1, 3 * HSZ * HSZ);
  split2_f64<<<(ISZ * HSZ + 255) / 256, 256, 0, stream>>>(w_sn_f64, Ws0, Ws1, ISZ * HSZ);
  split2_f32<<<((int)BI + 255) / 256, 256, 0, stream>>>(inputs, X0, X1, (int)BI);

  // t = 0: h1 from inputs, then y0
  gru_first<<<dim3(BATCH / 128, 16), 256, 0, stream>>>(X0, X1, Wi0, Wi1, b_ih, b_hh, hFA);
  y_step<<<BATCH / 16, 64, 0, stream>>>(hFA, Ws0, Ws1, b_lin, out);

  float* hin = hFA;
  float* hout = hFB;
  for (int t = 1; t < TSZ; ++t) {
    gru_gates<<<dim3(BATCH / 128, 16), 256, 0, stream>>>(
        out + (size_t)(t - 1) * BATCH * 64, hin,
        Wi0, Wi1, Wh0, Wh1, b_ih, b_hh, hout);
    y_step<<<BATCH / 16, 64, 0, stream>>>(hout, Ws0, Ws1, b_lin,
                                          out + (size_t)t * BATCH * 64);
    float* tm = hin; hin = hout; hout = tm;
  }

  bn_part<<<dim3(TSZ, 16), 256, 0, stream>>>(out, psum, psum2);
  bn_final<<<TSZ, 64, 0, stream>>>(psum, psum2, meanb, istdb);
  bn_norm<<<2048, 256, 0, stream>>>(out, meanb, istdb, TSZ * BATCH * 64 / 4);
}

// Round 12
// 1626.479 us; speedup vs baseline: 9.4428x; 1.4364x over previous
//
#include <hip/hip_runtime.h>
#include <hip/hip_bf16.h>

// Session rules (hard-won):
// R6: grid.sync() ~125us on MI355X -- never persistent-coop for a tight recurrence.
// R7: folding w_ih@w_sn into the recurrence fails numerically (0.139, 3x repro).
//     Only value-preserving transformations of the R5 dataflow.
// R8/R9: L2 is flushed at kernel boundaries -> ~7MB/step compulsory L3 traffic;
//     XCD-affine mapping can't create cross-kernel L2 reuse. Fusion regressed (R8-R10).
// R9: occupancy clamp strangles VGPR; R10: compiler sinks register preloads (null).
// R11: fp32 h-state: simpler, null perf. Best-known structure: R5 two-kernel chain.
// R12: weights via global_load_lds burst (async DMA, no VGPR) + G4 XOR swizzle;
//      attacks serial cold-L2 load latency -- the last untested theory.

typedef __attribute__((ext_vector_type(8))) short short8;
typedef __attribute__((ext_vector_type(4))) float f32x4;
typedef __hip_bfloat16 bf16_t;

#define BATCH 4096
#define ISZ 64
#define HSZ 256
#define TSZ 64

__device__ __forceinline__ float sigm(float x) { return 1.f / (1.f + __expf(-x)); }
__device__ __forceinline__ float tanh_fast(float x) { return 1.f - 2.f / (1.f + __expf(2.f * x)); }

// load 8 consecutive fp32 and split into two bf16 planes (in-register, RNE)
__device__ __forceinline__ void load_cvt(const float* __restrict__ p, short8& a0, short8& a1) {
  f32x4 u = *reinterpret_cast<const f32x4*>(p);
  f32x4 w = *reinterpret_cast<const f32x4*>(p + 4);
  float x[8] = {u[0], u[1], u[2], u[3], w[0], w[1], w[2], w[3]};
#pragma unroll
  for (int e = 0; e < 8; ++e) {
    bf16_t h0 = __float2bfloat16(x[e]);
    a0[e] = *reinterpret_cast<short*>(&h0);
    bf16_t h1 = __float2bfloat16(x[e] - __bfloat162float(h0));
    a1[e] = *reinterpret_cast<short*>(&h1);
  }
}

__device__ __forceinline__ void async16(const void* g, void* l) {
  __builtin_amdgcn_global_load_lds(
      (const __attribute__((address_space(1))) unsigned int*)g,
      (__attribute__((address_space(3))) unsigned int*)l, 16, 0, 0);
}

// ---------------- spectral norm prep, fp64 (1 block) ----------------
__global__ __launch_bounds__(256) void prep_sn(
    const float* __restrict__ w_lin, const float* __restrict__ u_sn,
    double* __restrict__ w_sn_f64)
{
  __shared__ double v[HSZ];
  __shared__ double red[256];
  __shared__ double Wv[ISZ];
  int t = threadIdx.x;
  double s = 0.0;
  for (int i = 0; i < ISZ; ++i) s += (double)w_lin[i * HSZ + t] * (double)u_sn[i];
  red[t] = s * s;
  __syncthreads();
  for (int off = 128; off > 0; off >>= 1) { if (t < off) red[t] += red[t + off]; __syncthreads(); }
  double nv = sqrt(red[0]);
  v[t] = s / (nv + 1e-12);
  __syncthreads();
  {
    int i = t >> 2, p = t & 3;
    double ps = 0.0;
    for (int k = p * 64; k < p * 64 + 64; ++k) ps += (double)w_lin[i * HSZ + k] * v[k];
    red[t] = ps;
    __syncthreads();
    if ((t & 3) == 0) Wv[i] = red[t] + red[t + 1] + red[t + 2] + red[t + 3];
    __syncthreads();
  }
  red[t] = (t < ISZ) ? Wv[t] * Wv[t] : 0.0;
  __syncthreads();
  for (int off = 128; off > 0; off >>= 1) { if (t < off) red[t] += red[t + off]; __syncthreads(); }
  double nw = sqrt(red[0]);
  double sigma = red[0] / (nw + 1e-12);  // u.(Wv), u = Wv/(|Wv|+eps)
  double inv_sigma = 1.0 / sigma;
  for (int idx = t; idx < ISZ * HSZ; idx += 256)
    w_sn_f64[idx] = (double)w_lin[idx] * inv_sigma;
}

// ---------------- 2-plane split casts (weights + t=0 inputs) ----------------
__global__ __launch_bounds__(256) void split2_f32(
    const float* __restrict__ x, bf16_t* __restrict__ p0, bf16_t* __restrict__ p1, int n)
{
  int i = blockIdx.x * 256 + threadIdx.x;
  if (i < n) {
    float v = x[i];
    bf16_t a = __float2bfloat16(v);
    p0[i] = a;
    p1[i] = __float2bfloat16(v - __bfloat162float(a));
  }
}

__global__ __launch_bounds__(256) void split2_f64(
    const double* __restrict__ x, bf16_t* __restrict__ p0, bf16_t* __restrict__ p1, int n)
{
  int i = blockIdx.x * 256 + threadIdx.x;
  if (i < n) {
    double v = x[i];
    bf16_t a = __float2bfloat16((float)v);
    p0[i] = a;
    p1[i] = __float2bfloat16((float)(v - (double)__bfloat162float(a)));
  }
}

// ---------------- t=0: gi from inputs, h1 = (1-z)*n -> fp32 ----------------
__global__ __launch_bounds__(256) void gru_first(
    const bf16_t* __restrict__ X0, const bf16_t* __restrict__ X1,
    const bf16_t* __restrict__ Wi0, const bf16_t* __restrict__ Wi1,
    const float* __restrict__ b_ih, const float* __restrict__ b_hh,
    float* __restrict__ hF)
{
  const int jb = blockIdx.y;
  const int mw = blockIdx.x * 128 + (threadIdx.x >> 6) * 32;
  const int l = threadIdx.x & 63;
  const int lr = l & 15;
  const int lq = l >> 4;
  const int j = jb * 16 + lr;

  f32x4 accM[2][3], accC[2][3];
#pragma unroll
  for (int mt = 0; mt < 2; ++mt)
#pragma unroll
    for (int g = 0; g < 3; ++g) {
      accM[mt][g] = (f32x4){0.f, 0.f, 0.f, 0.f};
      accC[mt][g] = (f32x4){0.f, 0.f, 0.f, 0.f};
    }

#pragma unroll
  for (int kk = 0; kk < ISZ; kk += 32) {
    short8 a0[2], a1[2];
#pragma unroll
    for (int mt = 0; mt < 2; ++mt) {
      size_t ao = (size_t)(mw + mt * 16 + lr) * ISZ + kk + lq * 8;
      a0[mt] = *reinterpret_cast<const short8*>(X0 + ao);
      a1[mt] = *reinterpret_cast<const short8*>(X1 + ao);
    }
#pragma unroll
    for (int g = 0; g < 3; ++g) {
      size_t bo = (size_t)(g * HSZ + jb * 16 + lr) * ISZ + kk + lq * 8;
      short8 b0 = *reinterpret_cast<const short8*>(Wi0 + bo);
      short8 b1 = *reinterpret_cast<const short8*>(Wi1 + bo);
#pragma unroll
      for (int mt = 0; mt < 2; ++mt) {
        accC[mt][g] = __builtin_amdgcn_mfma_f32_16x16x32_bf16(a0[mt], b1, accC[mt][g], 0, 0, 0);
        accC[mt][g] = __builtin_amdgcn_mfma_f32_16x16x32_bf16(a1[mt], b0, accC[mt][g], 0, 0, 0);
        accM[mt][g] = __builtin_amdgcn_mfma_f32_16x16x32_bf16(a0[mt], b0, accM[mt][g], 0, 0, 0);
      }
    }
  }

  const float brz = b_ih[j] + b_hh[j];
  const float bzz = b_ih[HSZ + j] + b_hh[HSZ + j];
  const float bin = b_ih[2 * HSZ + j];
  const float bhn = b_hh[2 * HSZ + j];

#pragma unroll
  for (int mt = 0; mt < 2; ++mt) {
#pragma unroll
    for (int q = 0; q < 4; ++q) {
      int b = mw + mt * 16 + lq * 4 + q;
      float r = sigm(accM[mt][0][q] + accC[mt][0][q] + brz);
      float z = sigm(accM[mt][1][q] + accC[mt][1][q] + bzz);
      float n = tanh_fast(accM[mt][2][q] + accC[mt][2][q] + bin + r * bhn);
      hF[(size_t)b * HSZ + j] = (1.f - z) * n;
    }
  }
}

// ---------------- gates step (t>=1): weights staged to LDS via global_load_lds ----------------
// Grid (BATCH/128, 16); block 256 = 4 waves; wave = 32 rows (2 mt) x 16 j.
// LDS: lWh[96][256] bf16 (rows R=(g*2+p)*16+jr, 512B rows), lWi[96][64] (128B rows).
// XOR swizzle byte ^= (R&7)<<4 applied to global SOURCE (linear LDS dest, rule #21)
// and to ds_read addresses. Same bf16 values, same MFMA order as R11 -> same absmax.
__global__ __launch_bounds__(256) void gru_gates(
    const float* __restrict__ yprev,  // out + (t-1)*BATCH*64
    const float* __restrict__ hF,     // [BATCH, 256] fp32
    const bf16_t* __restrict__ Wi0, const bf16_t* __restrict__ Wi1,
    const bf16_t* __restrict__ Wh0, const bf16_t* __restrict__ Wh1,
    const float* __restrict__ b_ih, const float* __restrict__ b_hh,
    float* __restrict__ hFo)
{
  __shared__ __align__(16) short lWh[96 * 256];  // 48 KB
  __shared__ __align__(16) short lWi[96 * 64];   // 12 KB

  const int jb = blockIdx.y;
  const int tid = threadIdx.x;
  const int wid = tid >> 6;
  const int mw = blockIdx.x * 128 + wid * 32;
  const int l = tid & 63;
  const int lr = l & 15;
  const int lq = l >> 4;
  const int j = jb * 16 + lr;

  // ---- async stage Wh (12 x 4KB) and Wi (3 x 4KB); linear LDS dest, swizzled source
#pragma unroll
  for (int i = 0; i < 12; ++i) {
    int L = i * 4096 + tid * 16;  // this thread's linear LDS byte slot
    int R = L >> 9, c16 = L & 511;
    int csrc = c16 ^ ((R & 7) << 4);
    int g = R >> 5, p = (R >> 4) & 1, jr = R & 15;
    const bf16_t* srcrow = (p ? Wh1 : Wh0) + (size_t)(g * HSZ + jb * 16 + jr) * HSZ;
    async16((const char*)srcrow + csrc, (char*)lWh + i * 4096 + wid * 1024);
  }
#pragma unroll
  for (int i = 0; i < 3; ++i) {
    int L = i * 4096 + tid * 16;
    int R = L >> 7, c16 = L & 127;
    int csrc = c16 ^ ((R & 7) << 4);
    int g = R >> 5, p = (R >> 4) & 1, jr = R & 15;
    const bf16_t* srcrow = (p ? Wi1 : Wi0) + (size_t)(g * HSZ + jb * 16 + jr) * ISZ;
    async16((const char*)srcrow + csrc, (char*)lWi + i * 4096 + wid * 1024);
  }

  // hold: one fp32 load per output element (issues while staging is in flight)
  float hold_[2][4];
#pragma unroll
  for (int mt = 0; mt < 2; ++mt)
#pragma unroll
    for (int q = 0; q < 4; ++q)
      hold_[mt][q] = hF[(size_t)(mw + mt * 16 + lq * 4 + q) * HSZ + j];

  asm volatile("s_waitcnt vmcnt(0)" ::: "memory");
  __syncthreads();

  f32x4 accM[2][4], accC[2][4];
#pragma unroll
  for (int mt = 0; mt < 2; ++mt)
#pragma unroll
    for (int g = 0; g < 4; ++g) {
      accM[mt][g] = (f32x4){0.f, 0.f, 0.f, 0.f};
      accC[mt][g] = (f32x4){0.f, 0.f, 0.f, 0.f};
    }

  // B-fragment LDS readers (swizzled): Wh row stride 512B, Wi 128B; R&7 == lr&7
  auto whf = [&](int g, int p, int c) -> short8 {
    int R = (g * 2 + p) * 16 + lr;
    int byte = R * 512 + ((c * 64 + lq * 16) ^ ((lr & 7) << 4));
    return *reinterpret_cast<const short8*>((const char*)lWh + byte);
  };
  auto wif = [&](int g, int p, int c) -> short8 {
    int R = (g * 2 + p) * 16 + lr;
    int byte = R * 128 + ((c * 64 + lq * 16) ^ ((lr & 7) << 4));
    return *reinterpret_cast<const short8*>((const char*)lWi + byte);
  };

  // ---- gi: x = split2(yprev) @ w_ih.T (K=64); gates 0,1,2 -> cols 0,1,2
#pragma unroll
  for (int c = 0; c < 2; ++c) {
    short8 a0[2], a1[2];
#pragma unroll
    for (int mt = 0; mt < 2; ++mt)
      load_cvt(yprev + (size_t)(mw + mt * 16 + lr) * ISZ + c * 32 + lq * 8, a0[mt], a1[mt]);
#pragma unroll
    for (int g = 0; g < 3; ++g) {
      short8 b0 = wif(g, 0, c);
      short8 b1 = wif(g, 1, c);
#pragma unroll
      for (int mt = 0; mt < 2; ++mt) {
        accC[mt][g] = __builtin_amdgcn_mfma_f32_16x16x32_bf16(a0[mt], b1, accC[mt][g], 0, 0, 0);
        accC[mt][g] = __builtin_amdgcn_mfma_f32_16x16x32_bf16(a1[mt], b0, accC[mt][g], 0, 0, 0);
        accM[mt][g] = __builtin_amdgcn_mfma_f32_16x16x32_bf16(a0[mt], b0, accM[mt][g], 0, 0, 0);
      }
    }
  }

  // ---- gh: h = split2(hF) @ w_hh.T (K=256); gates 0,1 -> cols 0,1; gate 2 -> col 3
#pragma unroll
  for (int c = 0; c < 8; ++c) {
    short8 a0[2], a1[2];
#pragma unroll
    for (int mt = 0; mt < 2; ++mt)
      load_cvt(hF + (size_t)(mw + mt * 16 + lr) * HSZ + c * 32 + lq * 8, a0[mt], a1[mt]);
#pragma unroll
    for (int g = 0; g < 3; ++g) {
      const int tgt = (g == 2) ? 3 : g;
      short8 b0 = whf(g, 0, c);
      short8 b1 = whf(g, 1, c);
#pragma unroll
      for (int mt = 0; mt < 2; ++mt) {
        accC[mt][tgt] = __builtin_amdgcn_mfma_f32_16x16x32_bf16(a0[mt], b1, accC[mt][tgt], 0, 0, 0);
        accC[mt][tgt] = __builtin_amdgcn_mfma_f32_16x16x32_bf16(a1[mt], b0, accC[mt][tgt], 0, 0, 0);
        accM[mt][tgt] = __builtin_amdgcn_mfma_f32_16x16x32_bf16(a0[mt], b0, accM[mt][tgt], 0, 0, 0);
      }
    }
  }

  const float brz = b_ih[j] + b_hh[j];
  const float bzz = b_ih[HSZ + j] + b_hh[HSZ + j];
  const float bin = b_ih[2 * HSZ + j];
  const float bhn = b_hh[2 * HSZ + j];

#pragma unroll
  for (int mt = 0; mt < 2; ++mt) {
#pragma unroll
    for (int q = 0; q < 4; ++q) {
      int b = mw + mt * 16 + lq * 4 + q;  // C/D: row=(lane>>4)*4+reg, col=lane&15
      float rpre = accM[mt][0][q] + accC[mt][0][q] + brz;
      float zpre = accM[mt][1][q] + accC[mt][1][q] + bzz;
      float inn  = accM[mt][2][q] + accC[mt][2][q] + bin;
      float hnn  = accM[mt][3][q] + accC[mt][3][q] + bhn;
      float r = sigm(rpre);
      float z = sigm(zpre);
      float n = tanh_fast(inn + r * hnn);
      double hv = (double)((1.f - z) * n) + (double)z * (double)hold_[mt][q];
      hFo[(size_t)b * HSZ + j] = (float)hv;
    }
  }
}

// ---------------- y_step: out[t] = split2(hF) @ w_sn.T + b_lin ----------------
__global__ __launch_bounds__(64) void y_step(
    const float* __restrict__ hF,
    const bf16_t* __restrict__ Ws0, const bf16_t* __restrict__ Ws1,
    const float* __restrict__ b_lin,
    float* __restrict__ yout)  // out + t*BATCH*64
{
  const int mw = blockIdx.x * 16;
  const int l = threadIdx.x;
  const int lr = l & 15;
  const int lq = l >> 4;

  f32x4 accM[4], accC[4];
#pragma unroll
  for (int nt = 0; nt < 4; ++nt) {
    accM[nt] = (f32x4){0.f, 0.f, 0.f, 0.f};
    accC[nt] = (f32x4){0.f, 0.f, 0.f, 0.f};
  }

  for (int kk = 0; kk < HSZ; kk += 32) {
    short8 a0, a1;
    load_cvt(hF + (size_t)(mw + lr) * HSZ + kk + lq * 8, a0, a1);
#pragma unroll
    for (int nt = 0; nt < 4; ++nt) {
      size_t bo = (size_t)(nt * 16 + lr) * HSZ + kk + lq * 8;
      short8 b0 = *reinterpret_cast<const short8*>(Ws0 + bo);
      short8 b1 = *reinterpret_cast<const short8*>(Ws1 + bo);
      accC[nt] = __builtin_amdgcn_mfma_f32_16x16x32_bf16(a0, b1, accC[nt], 0, 0, 0);
      accC[nt] = __builtin_amdgcn_mfma_f32_16x16x32_bf16(a1, b0, accC[nt], 0, 0, 0);
      accM[nt] = __builtin_amdgcn_mfma_f32_16x16x32_bf16(a0, b0, accM[nt], 0, 0, 0);
    }
  }

#pragma unroll
  for (int q = 0; q < 4; ++q) {
    size_t row = mw + lq * 4 + q;
#pragma unroll
    for (int nt = 0; nt < 4; ++nt) {
      int o = nt * 16 + lr;
      yout[row * 64 + o] = accM[nt][q] + accC[nt][q] + b_lin[o];
    }
  }
}

// ---------------- BatchNorm: two-stage stats + normalize ----------------
__global__ __launch_bounds__(256) void bn_part(const float* __restrict__ Y,
                                               double* __restrict__ psum,
                                               double* __restrict__ psum2)
{
  int t = blockIdx.x;
  int chunk = blockIdx.y;
  int o = threadIdx.x & 63, rg = threadIdx.x >> 6;
  const float* Yt = Y + (size_t)t * BATCH * 64;
  int b0 = chunk * 256;
  double s = 0.0, s2 = 0.0;
  for (int b = b0 + rg; b < b0 + 256; b += 4) {
    double v = (double)Yt[(size_t)b * 64 + o];
    s += v;
    s2 += v * v;
  }
  __shared__ double ls[4][64], ls2[4][64];
  ls[rg][o] = s;
  ls2[rg][o] = s2;
  __syncthreads();
  if (rg == 0) {
    s = ls[0][o] + ls[1][o] + ls[2][o] + ls[3][o];
    s2 = ls2[0][o] + ls2[1][o] + ls2[2][o] + ls2[3][o];
    size_t pi = ((size_t)t * 16 + chunk) * 64 + o;
    psum[pi] = s;
    psum2[pi] = s2;
  }
}

__global__ __launch_bounds__(64) void bn_final(const double* __restrict__ psum,
                                               const double* __restrict__ psum2,
                                               float* __restrict__ mean,
                                               float* __restrict__ istd)
{
  int t = blockIdx.x;
  int o = threadIdx.x;
  double s = 0.0, s2 = 0.0;
  for (int c = 0; c < 16; ++c) {
    size_t pi = ((size_t)t * 16 + c) * 64 + o;
    s += psum[pi];
    s2 += psum2[pi];
  }
  double m = s * (1.0 / BATCH);
  double var = s2 * (1.0 / BATCH) - m * m;
  mean[t * 64 + o] = (float)m;
  istd[t * 64 + o] = (float)(1.0 / sqrt(var + 1e-5));
}

__global__ __launch_bounds__(256) void bn_norm(float* __restrict__ Y,
                                               const float* __restrict__ mean,
                                               const float* __restrict__ istd, int n4)
{
  for (int i = blockIdx.x * 256 + threadIdx.x; i < n4; i += gridDim.x * 256) {
    f32x4 v = reinterpret_cast<f32x4*>(Y)[i];
    int base = i * 4;
    int o = base & 63;
    int t = base >> 18;  // / (BATCH*64)
    const float* mr = mean + t * 64;
    const float* ir = istd + t * 64;
#pragma unroll
    for (int e = 0; e < 4; ++e) v[e] = (v[e] - mr[o + e]) * ir[o + e];
    reinterpret_cast<f32x4*>(Y)[i] = v;
  }
}

extern "C" void kernel_launch(void* const* d_in, const int* in_sizes, int n_in,
                              void* d_out, int out_size, void* d_ws, size_t ws_size,
                              hipStream_t stream)
{
  const float* inputs = (const float*)d_in[0];
  const float* w_ih = (const float*)d_in[1];
  const float* w_hh = (const float*)d_in[2];
  const float* b_ih = (const float*)d_in[3];
  const float* b_hh = (const float*)d_in[4];
  const float* w_lin = (const float*)d_in[5];
  const float* b_lin = (const float*)d_in[6];
  const float* u_sn = (const float*)d_in[7];
  float* out = (float*)d_out;

  const size_t BH = (size_t)BATCH * HSZ;
  const size_t BI = (size_t)BATCH * ISZ;

  char* ws = (char*)d_ws;
  size_t off = 0;
  auto alloc = [&](size_t bytes) -> void* {
    void* p = ws + off;
    off += (bytes + 255) & ~(size_t)255;
    return p;
  };
  double* w_sn_f64 = (double*)alloc((size_t)ISZ * HSZ * 8);
  bf16_t* Wi0 = (bf16_t*)alloc((size_t)3 * HSZ * ISZ * 2);
  bf16_t* Wi1 = (bf16_t*)alloc((size_t)3 * HSZ * ISZ * 2);
  bf16_t* Wh0 = (bf16_t*)alloc((size_t)3 * HSZ * HSZ * 2);
  bf16_t* Wh1 = (bf16_t*)alloc((size_t)3 * HSZ * HSZ * 2);
  bf16_t* Ws0 = (bf16_t*)alloc((size_t)ISZ * HSZ * 2);
  bf16_t* Ws1 = (bf16_t*)alloc((size_t)ISZ * HSZ * 2);
  bf16_t* X0 = (bf16_t*)alloc(BI * 2);
  bf16_t* X1 = (bf16_t*)alloc(BI * 2);
  float* hFA = (float*)alloc(BH * 4);
  float* hFB = (float*)alloc(BH * 4);
  double* psum = (double*)alloc((size_t)TSZ * 16 * 64 * 8);
  double* psum2 = (double*)alloc((size_t)TSZ * 16 * 64 * 8);
  float* meanb = (float*)alloc(TSZ * 64 * 4);
  float* istdb = (float*)alloc(TSZ * 64 * 4);
  if (off > ws_size) return;

  prep_sn<<<1, 256, 0, stream>>>(w_lin, u_sn, w_sn_f64);
  split2_f32<<<(3 * HSZ * ISZ + 255) / 256, 256, 0, stream>>>(w_ih, Wi0, Wi1, 3 * HSZ * ISZ);
  split2_f32<<<(3 * HSZ * HSZ + 255) / 256, 256, 0, stream>>>(w_hh, Wh0, Wh1, 3 * HSZ * HSZ);
  split2_f64<<<(ISZ * HSZ + 255) / 256, 256, 0, stream>>>(w_sn_f64, Ws0, Ws1, ISZ * HSZ);
  split2_f32<<<((int)BI + 255) / 256, 256, 0, stream>>>(inputs, X0, X1, (int)BI);

  // t = 0: h1 from inputs, then y0
  gru_first<<<dim3(BATCH / 128, 16), 256, 0, stream>>>(X0, X1, Wi0, Wi1, b_ih, b_hh, hFA);
  y_step<<<BATCH / 16, 64, 0, stream>>>(hFA, Ws0, Ws1, b_lin, out);

  float* hin = hFA;
  float* hout = hFB;
  for (int t = 1; t < TSZ; ++t) {
    gru_gates<<<dim3(BATCH / 128, 16), 256, 0, stream>>>(
        out + (size_t)(t - 1) * BATCH * 64, hin,
        Wi0, Wi1, Wh0, Wh1, b_ih, b_hh, hout);
    y_step<<<BATCH / 16, 64, 0, stream>>>(hout, Ws0, Ws1, b_lin,
                                          out + (size_t)t * BATCH * 64);
    float* tm = hin; hin = hout; hout = tm;
  }

  bn_part<<<dim3(TSZ, 16), 256, 0, stream>>>(out, psum, psum2);
  bn_final<<<TSZ, 64, 0, stream>>>(psum, psum2, meanb, istdb);
  bn_norm<<<2048, 256, 0, stream>>>(out, meanb, istdb, TSZ * BATCH * 64 / 4);
}

// Round 13
// 1456.434 us; speedup vs baseline: 10.5453x; 1.1168x over previous
//
#include <hip/hip_runtime.h>
#include <hip/hip_bf16.h>

// Session rules (hard-won):
// R6: grid.sync() ~125us on MI355X -- never persistent-coop for a tight recurrence.
// R7: folding w_ih@w_sn into the recurrence fails numerically (0.139, 3x repro).
//     Only value-preserving transformations of the R5 dataflow.
// R8/R9: L2 is flushed at kernel boundaries -> ~7MB/step compulsory L3 traffic;
//     XCD-affine mapping can't create cross-kernel L2 reuse. Fusion regressed (R8-R10).
// R9: occupancy clamp strangles VGPR; R10: compiler sinks register preloads (null).
// R11: fp32 h-state: simpler, null perf.
// R12 WIN (2336->1626): global_load_lds weight staging -- serial cold-L2 B-load
//     latency was the bottleneck. Keep this structure.
// R13: y_step was 1 wave/CU (256 one-wave blocks); split over 4 col-tiles ->
//     1024 blocks, 4 waves/CU. Same MFMA order per accumulator -> bit-identical.

typedef __attribute__((ext_vector_type(8))) short short8;
typedef __attribute__((ext_vector_type(4))) float f32x4;
typedef __hip_bfloat16 bf16_t;

#define BATCH 4096
#define ISZ 64
#define HSZ 256
#define TSZ 64

__device__ __forceinline__ float sigm(float x) { return 1.f / (1.f + __expf(-x)); }
__device__ __forceinline__ float tanh_fast(float x) { return 1.f - 2.f / (1.f + __expf(2.f * x)); }

// load 8 consecutive fp32 and split into two bf16 planes (in-register, RNE)
__device__ __forceinline__ void load_cvt(const float* __restrict__ p, short8& a0, short8& a1) {
  f32x4 u = *reinterpret_cast<const f32x4*>(p);
  f32x4 w = *reinterpret_cast<const f32x4*>(p + 4);
  float x[8] = {u[0], u[1], u[2], u[3], w[0], w[1], w[2], w[3]};
#pragma unroll
  for (int e = 0; e < 8; ++e) {
    bf16_t h0 = __float2bfloat16(x[e]);
    a0[e] = *reinterpret_cast<short*>(&h0);
    bf16_t h1 = __float2bfloat16(x[e] - __bfloat162float(h0));
    a1[e] = *reinterpret_cast<short*>(&h1);
  }
}

__device__ __forceinline__ void async16(const void* g, void* l) {
  __builtin_amdgcn_global_load_lds(
      (const __attribute__((address_space(1))) unsigned int*)g,
      (__attribute__((address_space(3))) unsigned int*)l, 16, 0, 0);
}

// ---------------- spectral norm prep, fp64 (1 block) ----------------
__global__ __launch_bounds__(256) void prep_sn(
    const float* __restrict__ w_lin, const float* __restrict__ u_sn,
    double* __restrict__ w_sn_f64)
{
  __shared__ double v[HSZ];
  __shared__ double red[256];
  __shared__ double Wv[ISZ];
  int t = threadIdx.x;
  double s = 0.0;
  for (int i = 0; i < ISZ; ++i) s += (double)w_lin[i * HSZ + t] * (double)u_sn[i];
  red[t] = s * s;
  __syncthreads();
  for (int off = 128; off > 0; off >>= 1) { if (t < off) red[t] += red[t + off]; __syncthreads(); }
  double nv = sqrt(red[0]);
  v[t] = s / (nv + 1e-12);
  __syncthreads();
  {
    int i = t >> 2, p = t & 3;
    double ps = 0.0;
    for (int k = p * 64; k < p * 64 + 64; ++k) ps += (double)w_lin[i * HSZ + k] * v[k];
    red[t] = ps;
    __syncthreads();
    if ((t & 3) == 0) Wv[i] = red[t] + red[t + 1] + red[t + 2] + red[t + 3];
    __syncthreads();
  }
  red[t] = (t < ISZ) ? Wv[t] * Wv[t] : 0.0;
  __syncthreads();
  for (int off = 128; off > 0; off >>= 1) { if (t < off) red[t] += red[t + off]; __syncthreads(); }
  double nw = sqrt(red[0]);
  double sigma = red[0] / (nw + 1e-12);  // u.(Wv), u = Wv/(|Wv|+eps)
  double inv_sigma = 1.0 / sigma;
  for (int idx = t; idx < ISZ * HSZ; idx += 256)
    w_sn_f64[idx] = (double)w_lin[idx] * inv_sigma;
}

// ---------------- 2-plane split casts (weights + t=0 inputs) ----------------
__global__ __launch_bounds__(256) void split2_f32(
    const float* __restrict__ x, bf16_t* __restrict__ p0, bf16_t* __restrict__ p1, int n)
{
  int i = blockIdx.x * 256 + threadIdx.x;
  if (i < n) {
    float v = x[i];
    bf16_t a = __float2bfloat16(v);
    p0[i] = a;
    p1[i] = __float2bfloat16(v - __bfloat162float(a));
  }
}

__global__ __launch_bounds__(256) void split2_f64(
    const double* __restrict__ x, bf16_t* __restrict__ p0, bf16_t* __restrict__ p1, int n)
{
  int i = blockIdx.x * 256 + threadIdx.x;
  if (i < n) {
    double v = x[i];
    bf16_t a = __float2bfloat16((float)v);
    p0[i] = a;
    p1[i] = __float2bfloat16((float)(v - (double)__bfloat162float(a)));
  }
}

// ---------------- t=0: gi from inputs, h1 = (1-z)*n -> fp32 ----------------
__global__ __launch_bounds__(256) void gru_first(
    const bf16_t* __restrict__ X0, const bf16_t* __restrict__ X1,
    const bf16_t* __restrict__ Wi0, const bf16_t* __restrict__ Wi1,
    const float* __restrict__ b_ih, const float* __restrict__ b_hh,
    float* __restrict__ hF)
{
  const int jb = blockIdx.y;
  const int mw = blockIdx.x * 128 + (threadIdx.x >> 6) * 32;
  const int l = threadIdx.x & 63;
  const int lr = l & 15;
  const int lq = l >> 4;
  const int j = jb * 16 + lr;

  f32x4 accM[2][3], accC[2][3];
#pragma unroll
  for (int mt = 0; mt < 2; ++mt)
#pragma unroll
    for (int g = 0; g < 3; ++g) {
      accM[mt][g] = (f32x4){0.f, 0.f, 0.f, 0.f};
      accC[mt][g] = (f32x4){0.f, 0.f, 0.f, 0.f};
    }

#pragma unroll
  for (int kk = 0; kk < ISZ; kk += 32) {
    short8 a0[2], a1[2];
#pragma unroll
    for (int mt = 0; mt < 2; ++mt) {
      size_t ao = (size_t)(mw + mt * 16 + lr) * ISZ + kk + lq * 8;
      a0[mt] = *reinterpret_cast<const short8*>(X0 + ao);
      a1[mt] = *reinterpret_cast<const short8*>(X1 + ao);
    }
#pragma unroll
    for (int g = 0; g < 3; ++g) {
      size_t bo = (size_t)(g * HSZ + jb * 16 + lr) * ISZ + kk + lq * 8;
      short8 b0 = *reinterpret_cast<const short8*>(Wi0 + bo);
      short8 b1 = *reinterpret_cast<const short8*>(Wi1 + bo);
#pragma unroll
      for (int mt = 0; mt < 2; ++mt) {
        accC[mt][g] = __builtin_amdgcn_mfma_f32_16x16x32_bf16(a0[mt], b1, accC[mt][g], 0, 0, 0);
        accC[mt][g] = __builtin_amdgcn_mfma_f32_16x16x32_bf16(a1[mt], b0, accC[mt][g], 0, 0, 0);
        accM[mt][g] = __builtin_amdgcn_mfma_f32_16x16x32_bf16(a0[mt], b0, accM[mt][g], 0, 0, 0);
      }
    }
  }

  const float brz = b_ih[j] + b_hh[j];
  const float bzz = b_ih[HSZ + j] + b_hh[HSZ + j];
  const float bin = b_ih[2 * HSZ + j];
  const float bhn = b_hh[2 * HSZ + j];

#pragma unroll
  for (int mt = 0; mt < 2; ++mt) {
#pragma unroll
    for (int q = 0; q < 4; ++q) {
      int b = mw + mt * 16 + lq * 4 + q;
      float r = sigm(accM[mt][0][q] + accC[mt][0][q] + brz);
      float z = sigm(accM[mt][1][q] + accC[mt][1][q] + bzz);
      float n = tanh_fast(accM[mt][2][q] + accC[mt][2][q] + bin + r * bhn);
      hF[(size_t)b * HSZ + j] = (1.f - z) * n;
    }
  }
}

// ---------------- gates step (t>=1): weights staged to LDS via global_load_lds ----------------
// Grid (BATCH/128, 16); block 256 = 4 waves; wave = 32 rows (2 mt) x 16 j.
// LDS: lWh[96][256] bf16 (rows R=(g*2+p)*16+jr, 512B rows), lWi[96][64] (128B rows).
// XOR swizzle byte ^= (R&7)<<4 applied to global SOURCE (linear LDS dest, rule #21)
// and to ds_read addresses. Same bf16 values, same MFMA order as R11 -> same absmax.
__global__ __launch_bounds__(256) void gru_gates(
    const float* __restrict__ yprev,  // out + (t-1)*BATCH*64
    const float* __restrict__ hF,     // [BATCH, 256] fp32
    const bf16_t* __restrict__ Wi0, const bf16_t* __restrict__ Wi1,
    const bf16_t* __restrict__ Wh0, const bf16_t* __restrict__ Wh1,
    const float* __restrict__ b_ih, const float* __restrict__ b_hh,
    float* __restrict__ hFo)
{
  __shared__ __align__(16) short lWh[96 * 256];  // 48 KB
  __shared__ __align__(16) short lWi[96 * 64];   // 12 KB

  const int jb = blockIdx.y;
  const int tid = threadIdx.x;
  const int wid = tid >> 6;
  const int mw = blockIdx.x * 128 + wid * 32;
  const int l = tid & 63;
  const int lr = l & 15;
  const int lq = l >> 4;
  const int j = jb * 16 + lr;

  // ---- async stage Wh (12 x 4KB) and Wi (3 x 4KB); linear LDS dest, swizzled source
#pragma unroll
  for (int i = 0; i < 12; ++i) {
    int L = i * 4096 + tid * 16;  // this thread's linear LDS byte slot
    int R = L >> 9, c16 = L & 511;
    int csrc = c16 ^ ((R & 7) << 4);
    int g = R >> 5, p = (R >> 4) & 1, jr = R & 15;
    const bf16_t* srcrow = (p ? Wh1 : Wh0) + (size_t)(g * HSZ + jb * 16 + jr) * HSZ;
    async16((const char*)srcrow + csrc, (char*)lWh + i * 4096 + wid * 1024);
  }
#pragma unroll
  for (int i = 0; i < 3; ++i) {
    int L = i * 4096 + tid * 16;
    int R = L >> 7, c16 = L & 127;
    int csrc = c16 ^ ((R & 7) << 4);
    int g = R >> 5, p = (R >> 4) & 1, jr = R & 15;
    const bf16_t* srcrow = (p ? Wi1 : Wi0) + (size_t)(g * HSZ + jb * 16 + jr) * ISZ;
    async16((const char*)srcrow + csrc, (char*)lWi + i * 4096 + wid * 1024);
  }

  // hold: one fp32 load per output element (issues while staging is in flight)
  float hold_[2][4];
#pragma unroll
  for (int mt = 0; mt < 2; ++mt)
#pragma unroll
    for (int q = 0; q < 4; ++q)
      hold_[mt][q] = hF[(size_t)(mw + mt * 16 + lq * 4 + q) * HSZ + j];

  asm volatile("s_waitcnt vmcnt(0)" ::: "memory");
  __syncthreads();

  f32x4 accM[2][4], accC[2][4];
#pragma unroll
  for (int mt = 0; mt < 2; ++mt)
#pragma unroll
    for (int g = 0; g < 4; ++g) {
      accM[mt][g] = (f32x4){0.f, 0.f, 0.f, 0.f};
      accC[mt][g] = (f32x4){0.f, 0.f, 0.f, 0.f};
    }

  // B-fragment LDS readers (swizzled): Wh row stride 512B, Wi 128B; R&7 == lr&7
  auto whf = [&](int g, int p, int c) -> short8 {
    int R = (g * 2 + p) * 16 + lr;
    int byte = R * 512 + ((c * 64 + lq * 16) ^ ((lr & 7) << 4));
    return *reinterpret_cast<const short8*>((const char*)lWh + byte);
  };
  auto wif = [&](int g, int p, int c) -> short8 {
    int R = (g * 2 + p) * 16 + lr;
    int byte = R * 128 + ((c * 64 + lq * 16) ^ ((lr & 7) << 4));
    return *reinterpret_cast<const short8*>((const char*)lWi + byte);
  };

  // ---- gi: x = split2(yprev) @ w_ih.T (K=64); gates 0,1,2 -> cols 0,1,2
#pragma unroll
  for (int c = 0; c < 2; ++c) {
    short8 a0[2], a1[2];
#pragma unroll
    for (int mt = 0; mt < 2; ++mt)
      load_cvt(yprev + (size_t)(mw + mt * 16 + lr) * ISZ + c * 32 + lq * 8, a0[mt], a1[mt]);
#pragma unroll
    for (int g = 0; g < 3; ++g) {
      short8 b0 = wif(g, 0, c);
      short8 b1 = wif(g, 1, c);
#pragma unroll
      for (int mt = 0; mt < 2; ++mt) {
        accC[mt][g] = __builtin_amdgcn_mfma_f32_16x16x32_bf16(a0[mt], b1, accC[mt][g], 0, 0, 0);
        accC[mt][g] = __builtin_amdgcn_mfma_f32_16x16x32_bf16(a1[mt], b0, accC[mt][g], 0, 0, 0);
        accM[mt][g] = __builtin_amdgcn_mfma_f32_16x16x32_bf16(a0[mt], b0, accM[mt][g], 0, 0, 0);
      }
    }
  }

  // ---- gh: h = split2(hF) @ w_hh.T (K=256); gates 0,1 -> cols 0,1; gate 2 -> col 3
#pragma unroll
  for (int c = 0; c < 8; ++c) {
    short8 a0[2], a1[2];
#pragma unroll
    for (int mt = 0; mt < 2; ++mt)
      load_cvt(hF + (size_t)(mw + mt * 16 + lr) * HSZ + c * 32 + lq * 8, a0[mt], a1[mt]);
#pragma unroll
    for (int g = 0; g < 3; ++g) {
      const int tgt = (g == 2) ? 3 : g;
      short8 b0 = whf(g, 0, c);
      short8 b1 = whf(g, 1, c);
#pragma unroll
      for (int mt = 0; mt < 2; ++mt) {
        accC[mt][tgt] = __builtin_amdgcn_mfma_f32_16x16x32_bf16(a0[mt], b1, accC[mt][tgt], 0, 0, 0);
        accC[mt][tgt] = __builtin_amdgcn_mfma_f32_16x16x32_bf16(a1[mt], b0, accC[mt][tgt], 0, 0, 0);
        accM[mt][tgt] = __builtin_amdgcn_mfma_f32_16x16x32_bf16(a0[mt], b0, accM[mt][tgt], 0, 0, 0);
      }
    }
  }

  const float brz = b_ih[j] + b_hh[j];
  const float bzz = b_ih[HSZ + j] + b_hh[HSZ + j];
  const float bin = b_ih[2 * HSZ + j];
  const float bhn = b_hh[2 * HSZ + j];

#pragma unroll
  for (int mt = 0; mt < 2; ++mt) {
#pragma unroll
    for (int q = 0; q < 4; ++q) {
      int b = mw + mt * 16 + lq * 4 + q;  // C/D: row=(lane>>4)*4+reg, col=lane&15
      float rpre = accM[mt][0][q] + accC[mt][0][q] + brz;
      float zpre = accM[mt][1][q] + accC[mt][1][q] + bzz;
      float inn  = accM[mt][2][q] + accC[mt][2][q] + bin;
      float hnn  = accM[mt][3][q] + accC[mt][3][q] + bhn;
      float r = sigm(rpre);
      float z = sigm(zpre);
      float n = tanh_fast(inn + r * hnn);
      double hv = (double)((1.f - z) * n) + (double)z * (double)hold_[mt][q];
      hFo[(size_t)b * HSZ + j] = (float)hv;
    }
  }
}

// ---------------- y_step: out[t] = split2(hF) @ w_sn.T + b_lin ----------------
// R13: grid (BATCH/16, 4) one-wave blocks; wave = 16 rows x ONE 16-col tile
// (nt = blockIdx.y). 1024 blocks -> 4 waves/CU (was 1). Per-acc MFMA order
// identical to R12 -> bit-identical output.
__global__ __launch_bounds__(64) void y_step(
    const float* __restrict__ hF,
    const bf16_t* __restrict__ Ws0, const bf16_t* __restrict__ Ws1,
    const float* __restrict__ b_lin,
    float* __restrict__ yout)  // out + t*BATCH*64
{
  const int mw = blockIdx.x * 16;
  const int nt = blockIdx.y;
  const int l = threadIdx.x;
  const int lr = l & 15;
  const int lq = l >> 4;

  f32x4 accM = (f32x4){0.f, 0.f, 0.f, 0.f};
  f32x4 accC = (f32x4){0.f, 0.f, 0.f, 0.f};

  for (int kk = 0; kk < HSZ; kk += 32) {
    short8 a0, a1;
    load_cvt(hF + (size_t)(mw + lr) * HSZ + kk + lq * 8, a0, a1);
    size_t bo = (size_t)(nt * 16 + lr) * HSZ + kk + lq * 8;
    short8 b0 = *reinterpret_cast<const short8*>(Ws0 + bo);
    short8 b1 = *reinterpret_cast<const short8*>(Ws1 + bo);
    accC = __builtin_amdgcn_mfma_f32_16x16x32_bf16(a0, b1, accC, 0, 0, 0);
    accC = __builtin_amdgcn_mfma_f32_16x16x32_bf16(a1, b0, accC, 0, 0, 0);
    accM = __builtin_amdgcn_mfma_f32_16x16x32_bf16(a0, b0, accM, 0, 0, 0);
  }

  const int o = nt * 16 + lr;
  const float bl = b_lin[o];
#pragma unroll
  for (int q = 0; q < 4; ++q) {
    size_t row = mw + lq * 4 + q;
    yout[row * 64 + o] = accM[q] + accC[q] + bl;
  }
}

// ---------------- BatchNorm: two-stage stats + normalize ----------------
__global__ __launch_bounds__(256) void bn_part(const float* __restrict__ Y,
                                               double* __restrict__ psum,
                                               double* __restrict__ psum2)
{
  int t = blockIdx.x;
  int chunk = blockIdx.y;
  int o = threadIdx.x & 63, rg = threadIdx.x >> 6;
  const float* Yt = Y + (size_t)t * BATCH * 64;
  int b0 = chunk * 256;
  double s = 0.0, s2 = 0.0;
  for (int b = b0 + rg; b < b0 + 256; b += 4) {
    double v = (double)Yt[(size_t)b * 64 + o];
    s += v;
    s2 += v * v;
  }
  __shared__ double ls[4][64], ls2[4][64];
  ls[rg][o] = s;
  ls2[rg][o] = s2;
  __syncthreads();
  if (rg == 0) {
    s = ls[0][o] + ls[1][o] + ls[2][o] + ls[3][o];
    s2 = ls2[0][o] + ls2[1][o] + ls2[2][o] + ls2[3][o];
    size_t pi = ((size_t)t * 16 + chunk) * 64 + o;
    psum[pi] = s;
    psum2[pi] = s2;
  }
}

__global__ __launch_bounds__(64) void bn_final(const double* __restrict__ psum,
                                               const double* __restrict__ psum2,
                                               float* __restrict__ mean,
                                               float* __restrict__ istd)
{
  int t = blockIdx.x;
  int o = threadIdx.x;
  double s = 0.0, s2 = 0.0;
  for (int c = 0; c < 16; ++c) {
    size_t pi = ((size_t)t * 16 + c) * 64 + o;
    s += psum[pi];
    s2 += psum2[pi];
  }
  double m = s * (1.0 / BATCH);
  double var = s2 * (1.0 / BATCH) - m * m;
  mean[t * 64 + o] = (float)m;
  istd[t * 64 + o] = (float)(1.0 / sqrt(var + 1e-5));
}

__global__ __launch_bounds__(256) void bn_norm(float* __restrict__ Y,
                                               const float* __restrict__ mean,
                                               const float* __restrict__ istd, int n4)
{
  for (int i = blockIdx.x * 256 + threadIdx.x; i < n4; i += gridDim.x * 256) {
    f32x4 v = reinterpret_cast<f32x4*>(Y)[i];
    int base = i * 4;
    int o = base & 63;
    int t = base >> 18;  // / (BATCH*64)
    const float* mr = mean + t * 64;
    const float* ir = istd + t * 64;
#pragma unroll
    for (int e = 0; e < 4; ++e) v[e] = (v[e] - mr[o + e]) * ir[o + e];
    reinterpret_cast<f32x4*>(Y)[i] = v;
  }
}

extern "C" void kernel_launch(void* const* d_in, const int* in_sizes, int n_in,
                              void* d_out, int out_size, void* d_ws, size_t ws_size,
                              hipStream_t stream)
{
  const float* inputs = (const float*)d_in[0];
  const float* w_ih = (const float*)d_in[1];
  const float* w_hh = (const float*)d_in[2];
  const float* b_ih = (const float*)d_in[3];
  const float* b_hh = (const float*)d_in[4];
  const float* w_lin = (const float*)d_in[5];
  const float* b_lin = (const float*)d_in[6];
  const float* u_sn = (const float*)d_in[7];
  float* out = (float*)d_out;

  const size_t BH = (size_t)BATCH * HSZ;
  const size_t BI = (size_t)BATCH * ISZ;

  char* ws = (char*)d_ws;
  size_t off = 0;
  auto alloc = [&](size_t bytes) -> void* {
    void* p = ws + off;
    off += (bytes + 255) & ~(size_t)255;
    return p;
  };
  double* w_sn_f64 = (double*)alloc((size_t)ISZ * HSZ * 8);
  bf16_t* Wi0 = (bf16_t*)alloc((size_t)3 * HSZ * ISZ * 2);
  bf16_t* Wi1 = (bf16_t*)alloc((size_t)3 * HSZ * ISZ * 2);
  bf16_t* Wh0 = (bf16_t*)alloc((size_t)3 * HSZ * HSZ * 2);
  bf16_t* Wh1 = (bf16_t*)alloc((size_t)3 * HSZ * HSZ * 2);
  bf16_t* Ws0 = (bf16_t*)alloc((size_t)ISZ * HSZ * 2);
  bf16_t* Ws1 = (bf16_t*)alloc((size_t)ISZ * HSZ * 2);
  bf16_t* X0 = (bf16_t*)alloc(BI * 2);
  bf16_t* X1 = (bf16_t*)alloc(BI * 2);
  float* hFA = (float*)alloc(BH * 4);
  float* hFB = (float*)alloc(BH * 4);
  double* psum = (double*)alloc((size_t)TSZ * 16 * 64 * 8);
  double* psum2 = (double*)alloc((size_t)TSZ * 16 * 64 * 8);
  float* meanb = (float*)alloc(TSZ * 64 * 4);
  float* istdb = (float*)alloc(TSZ * 64 * 4);
  if (off > ws_size) return;

  prep_sn<<<1, 256, 0, stream>>>(w_lin, u_sn, w_sn_f64);
  split2_f32<<<(3 * HSZ * ISZ + 255) / 256, 256, 0, stream>>>(w_ih, Wi0, Wi1, 3 * HSZ * ISZ);
  split2_f32<<<(3 * HSZ * HSZ + 255) / 256, 256, 0, stream>>>(w_hh, Wh0, Wh1, 3 * HSZ * HSZ);
  split2_f64<<<(ISZ * HSZ + 255) / 256, 256, 0, stream>>>(w_sn_f64, Ws0, Ws1, ISZ * HSZ);
  split2_f32<<<((int)BI + 255) / 256, 256, 0, stream>>>(inputs, X0, X1, (int)BI);

  // t = 0: h1 from inputs, then y0
  gru_first<<<dim3(BATCH / 128, 16), 256, 0, stream>>>(X0, X1, Wi0, Wi1, b_ih, b_hh, hFA);
  y_step<<<dim3(BATCH / 16, 4), 64, 0, stream>>>(hFA, Ws0, Ws1, b_lin, out);

  float* hin = hFA;
  float* hout = hFB;
  for (int t = 1; t < TSZ; ++t) {
    gru_gates<<<dim3(BATCH / 128, 16), 256, 0, stream>>>(
        out + (size_t)(t - 1) * BATCH * 64, hin,
        Wi0, Wi1, Wh0, Wh1, b_ih, b_hh, hout);
    y_step<<<dim3(BATCH / 16, 4), 64, 0, stream>>>(hout, Ws0, Ws1, b_lin,
                                                   out + (size_t)t * BATCH * 64);
    float* tm = hin; hin = hout; hout = tm;
  }

  bn_part<<<dim3(TSZ, 16), 256, 0, stream>>>(out, psum, psum2);
  bn_final<<<TSZ, 64, 0, stream>>>(psum, psum2, meanb, istdb);
  bn_norm<<<2048, 256, 0, stream>>>(out, meanb, istdb, TSZ * BATCH * 64 / 4);
}